// Round 1
// baseline (4045.065 us; speedup 1.0000x reference)
//
#include <hip/hip_runtime.h>
#include <math.h>

#define DD 512

__device__ __forceinline__ float silu_f(float x) { return x / (1.f + __expf(-x)); }
__device__ __forceinline__ float gelu_f(float x) { return 0.5f * x * (1.f + erff(x * 0.7071067811865475f)); }

// ---------------- generic tiled fp32 GEMM ----------------
// C[M,N] = act(A[M,K] @ W[K,N] + bias[N]) + res_scale * res[M,N]
// ACT: 0 = none, 1 = exact GELU. K % 16 == 0, N % 128 == 0 assumed; M ragged ok.
template<int ACT>
__global__ __launch_bounds__(256) void gemm_k(
    const float* __restrict__ A, const float* __restrict__ W,
    const float* __restrict__ bias, const float* __restrict__ res,
    float res_scale, float* __restrict__ C, int M, int N, int K)
{
  __shared__ float As[16][132];
  __shared__ float Bs[16][132];
  const int tid = threadIdx.x;
  const int tx = tid & 15, ty = tid >> 4;
  const int bm = blockIdx.y << 7, bn = blockIdx.x << 7;
  float acc[8][8];
#pragma unroll
  for (int i = 0; i < 8; ++i)
#pragma unroll
    for (int j = 0; j < 8; ++j) acc[i][j] = 0.f;

  for (int k0 = 0; k0 < K; k0 += 16) {
    __syncthreads();
#pragma unroll
    for (int i = 0; i < 2; ++i) {
      int f = tid + (i << 8);
      int row = f >> 2, c4 = (f & 3) << 2;
      float4 a4 = make_float4(0.f, 0.f, 0.f, 0.f);
      if (bm + row < M) a4 = *(const float4*)(A + (size_t)(bm + row) * K + k0 + c4);
      As[c4 + 0][row] = a4.x; As[c4 + 1][row] = a4.y;
      As[c4 + 2][row] = a4.z; As[c4 + 3][row] = a4.w;
    }
#pragma unroll
    for (int i = 0; i < 2; ++i) {
      int f = tid + (i << 8);
      int row = f >> 5, c4 = (f & 31) << 2;
      *(float4*)&Bs[row][c4] = *(const float4*)(W + (size_t)(k0 + row) * N + bn + c4);
    }
    __syncthreads();
#pragma unroll
    for (int kk = 0; kk < 16; ++kk) {
      float a[8], b[8];
      *(float4*)&a[0] = *(float4*)&As[kk][ty * 8];
      *(float4*)&a[4] = *(float4*)&As[kk][ty * 8 + 4];
      *(float4*)&b[0] = *(float4*)&Bs[kk][tx * 8];
      *(float4*)&b[4] = *(float4*)&Bs[kk][tx * 8 + 4];
#pragma unroll
      for (int i = 0; i < 8; ++i)
#pragma unroll
        for (int j = 0; j < 8; ++j) acc[i][j] = fmaf(a[i], b[j], acc[i][j]);
    }
  }

#pragma unroll
  for (int i = 0; i < 8; ++i) {
    int m = bm + ty * 8 + i;
    if (m < M) {
#pragma unroll
      for (int j4 = 0; j4 < 2; ++j4) {
        int n = bn + tx * 8 + j4 * 4;
        float4 bi = *(const float4*)(bias + n);
        float o[4];
#pragma unroll
        for (int j = 0; j < 4; ++j) o[j] = acc[i][j4 * 4 + j];
        o[0] += bi.x; o[1] += bi.y; o[2] += bi.z; o[3] += bi.w;
        if (ACT == 1) {
#pragma unroll
          for (int j = 0; j < 4; ++j) o[j] = gelu_f(o[j]);
        }
        if (res) {
          float4 r = *(const float4*)(res + (size_t)m * N + n);
          o[0] += res_scale * r.x; o[1] += res_scale * r.y;
          o[2] += res_scale * r.z; o[3] += res_scale * r.w;
        }
        *(float4*)(C + (size_t)m * N + n) = make_float4(o[0], o[1], o[2], o[3]);
      }
    }
  }
}

// ---------------- LayerNorm over D=512, optional fused SiLU on output ----------------
__global__ __launch_bounds__(256) void ln_k(
    const float* __restrict__ src, const float* __restrict__ g,
    const float* __restrict__ b, float* __restrict__ out, int rows, int do_silu)
{
  int lane = threadIdx.x & 63, wv = threadIdx.x >> 6;
  int row = (blockIdx.x << 2) + wv;
  if (row >= rows) return;
  const float* p = src + (size_t)row * DD;
  float4 v0 = *(const float4*)(p + lane * 4);
  float4 v1 = *(const float4*)(p + 256 + lane * 4);
  float s = v0.x + v0.y + v0.z + v0.w + v1.x + v1.y + v1.z + v1.w;
  float ss = v0.x*v0.x + v0.y*v0.y + v0.z*v0.z + v0.w*v0.w
           + v1.x*v1.x + v1.y*v1.y + v1.z*v1.z + v1.w*v1.w;
#pragma unroll
  for (int m = 1; m < 64; m <<= 1) { s += __shfl_xor(s, m); ss += __shfl_xor(ss, m); }
  float mean = s * (1.f / 512.f);
  float var = ss * (1.f / 512.f) - mean * mean;
  float rstd = rsqrtf(var + 1e-5f);
  float4 g0 = *(const float4*)(g + lane * 4);
  float4 g1 = *(const float4*)(g + 256 + lane * 4);
  float4 b0 = *(const float4*)(b + lane * 4);
  float4 b1 = *(const float4*)(b + 256 + lane * 4);
  float4 o0, o1;
  o0.x = (v0.x - mean) * rstd * g0.x + b0.x;
  o0.y = (v0.y - mean) * rstd * g0.y + b0.y;
  o0.z = (v0.z - mean) * rstd * g0.z + b0.z;
  o0.w = (v0.w - mean) * rstd * g0.w + b0.w;
  o1.x = (v1.x - mean) * rstd * g1.x + b1.x;
  o1.y = (v1.y - mean) * rstd * g1.y + b1.y;
  o1.z = (v1.z - mean) * rstd * g1.z + b1.z;
  o1.w = (v1.w - mean) * rstd * g1.w + b1.w;
  if (do_silu) {
    o0.x = silu_f(o0.x); o0.y = silu_f(o0.y); o0.z = silu_f(o0.z); o0.w = silu_f(o0.w);
    o1.x = silu_f(o1.x); o1.y = silu_f(o1.y); o1.z = silu_f(o1.z); o1.w = silu_f(o1.w);
  }
  *(float4*)(out + (size_t)row * DD + lane * 4) = o0;
  *(float4*)(out + (size_t)row * DD + 256 + lane * 4) = o1;
}

// ---------------- self-attention: one thread per query row, online softmax (no max; scores are tiny) ----
// out = silu(attn_out), grid = B*H*4 blocks of 256 threads
__global__ __launch_bounds__(256) void attn_k(
    const float* __restrict__ q, const float* __restrict__ k,
    const float* __restrict__ v, float* __restrict__ out)
{
  __shared__ float Ks[64][68];
  __shared__ float Vs[64][68];
  int blk = blockIdx.x;
  int tc = blk & 3, h = (blk >> 2) & 7, b = blk >> 5;
  int t = (tc << 8) + threadIdx.x;
  const float* qp = q + ((size_t)(b * 1024 + t)) * DD + h * 64;
  float qr[64];
#pragma unroll
  for (int j = 0; j < 16; ++j) {
    float4 t4 = *(const float4*)(qp + j * 4);
    qr[j*4+0] = t4.x; qr[j*4+1] = t4.y; qr[j*4+2] = t4.z; qr[j*4+3] = t4.w;
  }
  float acc[64];
#pragma unroll
  for (int j = 0; j < 64; ++j) acc[j] = 0.f;
  float l = 0.f;
  for (int st = 0; st < 16; ++st) {
    __syncthreads();
#pragma unroll
    for (int i = 0; i < 4; ++i) {
      int f = threadIdx.x + (i << 8);
      int row = f >> 4, c4 = (f & 15) << 2;
      size_t src = ((size_t)(b * 1024 + (st << 6) + row)) * DD + h * 64 + c4;
      *(float4*)&Ks[row][c4] = *(const float4*)(k + src);
      *(float4*)&Vs[row][c4] = *(const float4*)(v + src);
    }
    __syncthreads();
    for (int ss = 0; ss < 64; ++ss) {
      float sc = 0.f;
#pragma unroll
      for (int j = 0; j < 16; ++j) {
        float4 k4 = *(const float4*)&Ks[ss][j * 4];
        sc = fmaf(qr[j*4+0], k4.x, sc); sc = fmaf(qr[j*4+1], k4.y, sc);
        sc = fmaf(qr[j*4+2], k4.z, sc); sc = fmaf(qr[j*4+3], k4.w, sc);
      }
      float e = __expf(sc * 0.125f);
      l += e;
#pragma unroll
      for (int j = 0; j < 16; ++j) {
        float4 v4 = *(const float4*)&Vs[ss][j * 4];
        acc[j*4+0] = fmaf(e, v4.x, acc[j*4+0]); acc[j*4+1] = fmaf(e, v4.y, acc[j*4+1]);
        acc[j*4+2] = fmaf(e, v4.z, acc[j*4+2]); acc[j*4+3] = fmaf(e, v4.w, acc[j*4+3]);
      }
    }
  }
  float inv = 1.f / l;
  float* op = out + ((size_t)(b * 1024 + t)) * DD + h * 64;
#pragma unroll
  for (int j = 0; j < 16; ++j) {
    float4 o;
    o.x = silu_f(acc[j*4+0] * inv); o.y = silu_f(acc[j*4+1] * inv);
    o.z = silu_f(acc[j*4+2] * inv); o.w = silu_f(acc[j*4+3] * inv);
    *(float4*)(op + j * 4) = o;
  }
}

// ---------------- softmax over contiguous rows of 64 (cq), in-place ----------------
__global__ __launch_bounds__(256) void softmax64_k(float* __restrict__ p, int rows)
{
  int lane = threadIdx.x & 63, wv = threadIdx.x >> 6;
  int row = (blockIdx.x << 2) + wv;
  if (row >= rows) return;
  float x = p[(size_t)row * 64 + lane];
  float m = x;
#pragma unroll
  for (int mk = 1; mk < 64; mk <<= 1) m = fmaxf(m, __shfl_xor(m, mk));
  float e = __expf(x - m);
  float s = e;
#pragma unroll
  for (int mk = 1; mk < 64; mk <<= 1) s += __shfl_xor(s, mk);
  p[(size_t)row * 64 + lane] = e / s;
}

// ---------------- softmax over sequence axis (stride 512), in-place ----------------
// grid = B*2 blocks, thread = one of 512 columns
__global__ __launch_bounds__(256) void softmax_seq_k(float* __restrict__ p, int nlen)
{
  int b = blockIdx.x >> 1;
  int c = ((blockIdx.x & 1) << 8) + threadIdx.x;
  float* base = p + (size_t)b * nlen * DD + c;
  float m = -1e30f;
  for (int n = 0; n < nlen; ++n) m = fmaxf(m, base[(size_t)n * DD]);
  float s = 0.f;
  for (int n = 0; n < nlen; ++n) s += __expf(base[(size_t)n * DD] - m);
  float inv = 1.f / s;
  for (int n = 0; n < nlen; ++n) base[(size_t)n * DD] = __expf(base[(size_t)n * DD] - m) * inv;
}

// ---------------- build concat([xw, broadcast(xf_p)]) : [B,512,256] ----------------
__global__ __launch_bounds__(256) void build_xc_k(
    const float* __restrict__ xw, const float* __restrict__ xfp, float* __restrict__ xc)
{
  int idx = blockIdx.x * 256 + threadIdx.x;
  int c = idx & 255, n = (idx >> 8) & 511, b = idx >> 17;
  xc[idx] = (n < 256) ? xw[((b << 8) + n) * 256 + c] : xfp[(b << 8) + c];
}

// ---------------- att[b,h,d,l] = sum_n ck[b,n,h,d]*cv[b,n,h,l] ; grid = B*H ----------------
__global__ __launch_bounds__(256) void attmat_k(
    const float* __restrict__ ckp, const float* __restrict__ cvp,
    float* __restrict__ att, int nlen)
{
  __shared__ float a_s[64][68];
  __shared__ float b_s[64][68];
  int h = blockIdx.x & 7, b = blockIdx.x >> 3;
  int tid = threadIdx.x;
  int d = tid & 63, lg = tid >> 6;
  float acc[16];
#pragma unroll
  for (int j = 0; j < 16; ++j) acc[j] = 0.f;
  for (int n0 = 0; n0 < nlen; n0 += 64) {
    __syncthreads();
#pragma unroll
    for (int i = 0; i < 4; ++i) {
      int f = tid + (i << 8);
      int row = f >> 4, c4 = (f & 15) << 2;
      size_t src = ((size_t)(b * nlen + n0 + row)) * DD + h * 64 + c4;
      *(float4*)&a_s[row][c4] = *(const float4*)(ckp + src);
      *(float4*)&b_s[row][c4] = *(const float4*)(cvp + src);
    }
    __syncthreads();
    for (int nn = 0; nn < 64; ++nn) {
      float av = a_s[nn][d];
#pragma unroll
      for (int j4 = 0; j4 < 4; ++j4) {
        float4 b4 = *(float4*)&b_s[nn][lg * 16 + j4 * 4];
        acc[j4*4+0] = fmaf(av, b4.x, acc[j4*4+0]);
        acc[j4*4+1] = fmaf(av, b4.y, acc[j4*4+1]);
        acc[j4*4+2] = fmaf(av, b4.z, acc[j4*4+2]);
        acc[j4*4+3] = fmaf(av, b4.w, acc[j4*4+3]);
      }
    }
  }
  float* op = att + (size_t)(b * 8 + h) * 4096 + d * 64 + lg * 16;
#pragma unroll
  for (int j4 = 0; j4 < 4; ++j4)
    *(float4*)(op + j4 * 4) = make_float4(acc[j4*4+0], acc[j4*4+1], acc[j4*4+2], acc[j4*4+3]);
}

// ---------------- sy[b,h,l] = sum_s (sum_d sk[b,s,h,d]) * sv[b,s,h,l] ; grid B*H, 64 threads ----
__global__ __launch_bounds__(64) void sy_k(
    const float* __restrict__ skp, const float* __restrict__ svp, float* __restrict__ sy)
{
  int h = blockIdx.x & 7, b = blockIdx.x >> 3;
  int lane = threadIdx.x;
  float acc = 0.f;
  for (int s = 0; s < 256; ++s) {
    size_t base = ((size_t)(b * 256 + s)) * DD + h * 64 + lane;
    float w = skp[base];
#pragma unroll
    for (int m = 1; m < 64; m <<= 1) w += __shfl_xor(w, m);
    acc = fmaf(w, svp[base], acc);
  }
  sy[(b * 8 + h) * 64 + lane] = acc;
}

// ---------------- out = silu(cq @ att + sy) ; grid = B*H*16 (t-tiles of 64) ----------------
__global__ __launch_bounds__(256) void cy_k(
    const float* __restrict__ cq, const float* __restrict__ att,
    const float* __restrict__ sy, float* __restrict__ out)
{
  __shared__ float atts[64][68];
  __shared__ float qs[64][68];
  __shared__ float sys[64];
  int blk = blockIdx.x;
  int tt = blk & 15, h = (blk >> 4) & 7, b = blk >> 7;
  int t0 = tt << 6;
  int tid = threadIdx.x;
#pragma unroll
  for (int i = 0; i < 4; ++i) {
    int f = tid + (i << 8);
    int row = f >> 4, c4 = (f & 15) << 2;
    *(float4*)&atts[row][c4] = *(const float4*)(att + (size_t)(b * 8 + h) * 4096 + row * 64 + c4);
    *(float4*)&qs[row][c4] = *(const float4*)(cq + ((size_t)(b * 1024 + t0 + row)) * DD + h * 64 + c4);
  }
  if (tid < 64) sys[tid] = sy[(b * 8 + h) * 64 + tid];
  __syncthreads();
  int r = tid >> 2, lg = tid & 3;
  float acc[16];
#pragma unroll
  for (int j = 0; j < 16; ++j) acc[j] = 0.f;
  for (int d = 0; d < 64; ++d) {
    float qv = qs[r][d];
#pragma unroll
    for (int j4 = 0; j4 < 4; ++j4) {
      float4 a4 = *(float4*)&atts[d][lg * 16 + j4 * 4];
      acc[j4*4+0] = fmaf(qv, a4.x, acc[j4*4+0]);
      acc[j4*4+1] = fmaf(qv, a4.y, acc[j4*4+1]);
      acc[j4*4+2] = fmaf(qv, a4.z, acc[j4*4+2]);
      acc[j4*4+3] = fmaf(qv, a4.w, acc[j4*4+3]);
    }
  }
  float* op = out + ((size_t)(b * 1024 + t0 + r)) * DD + h * 64 + lg * 16;
#pragma unroll
  for (int j4 = 0; j4 < 4; ++j4) {
    float4 o;
    o.x = silu_f(acc[j4*4+0] + sys[lg * 16 + j4*4+0]);
    o.y = silu_f(acc[j4*4+1] + sys[lg * 16 + j4*4+1]);
    o.z = silu_f(acc[j4*4+2] + sys[lg * 16 + j4*4+2]);
    o.w = silu_f(acc[j4*4+3] + sys[lg * 16 + j4*4+3]);
    *(float4*)(op + j4 * 4) = o;
  }
}

extern "C" void kernel_launch(void* const* d_in, const int* in_sizes, int n_in,
                              void* d_out, int out_size, void* d_ws, size_t ws_size,
                              hipStream_t stream)
{
  const float* x      = (const float*)d_in[0];
  const float* xf     = (const float*)d_in[1];
  const float* xw     = (const float*)d_in[2];
  const float* xs     = (const float*)d_in[3];
  const float* fp_w   = (const float*)d_in[4];
  const float* fp_b   = (const float*)d_in[5];
  const float* sa_ng  = (const float*)d_in[6];
  const float* sa_nb  = (const float*)d_in[7];
  const float* sa_qw  = (const float*)d_in[8];
  const float* sa_qb  = (const float*)d_in[9];
  const float* sa_kw  = (const float*)d_in[10];
  const float* sa_kb  = (const float*)d_in[11];
  const float* sa_vw  = (const float*)d_in[12];
  const float* sa_vb  = (const float*)d_in[13];
  const float* sa_ow  = (const float*)d_in[14];
  const float* sa_ob  = (const float*)d_in[15];
  const float* ca_ng  = (const float*)d_in[16];
  const float* ca_nb  = (const float*)d_in[17];
  const float* ca_tng = (const float*)d_in[18];
  const float* ca_tnb = (const float*)d_in[19];
  const float* ca_sng = (const float*)d_in[20];
  const float* ca_snb = (const float*)d_in[21];
  const float* ca_qw  = (const float*)d_in[22];
  const float* ca_qb  = (const float*)d_in[23];
  const float* ca_kw  = (const float*)d_in[24];
  const float* ca_kb  = (const float*)d_in[25];
  const float* ca_vw  = (const float*)d_in[26];
  const float* ca_vb  = (const float*)d_in[27];
  const float* ca_apw = (const float*)d_in[28];
  const float* ca_apb = (const float*)d_in[29];
  const float* ca_atw = (const float*)d_in[30];
  const float* ca_atb = (const float*)d_in[31];
  const float* ca_ow  = (const float*)d_in[32];
  const float* ca_ob  = (const float*)d_in[33];
  const float* an_g   = (const float*)d_in[34];
  const float* an_b   = (const float*)d_in[35];
  const float* ffn_w1 = (const float*)d_in[36];
  const float* ffn_b1 = (const float*)d_in[37];
  const float* ffn_w2 = (const float*)d_in[38];
  const float* ffn_b2 = (const float*)d_in[39];
  const float* ffn_ng = (const float*)d_in[40];
  const float* ffn_nb = (const float*)d_in[41];
  const float* ffn_ow = (const float*)d_in[42];
  const float* ffn_ob = (const float*)d_in[43];

  float* ws  = (float*)d_ws;
  float* xp  = ws;                    // 4194304
  float* xn  = ws + 4194304;          // 4194304  (also cysy_silu)
  float* q   = ws + 8388608;          // 4194304  (also z1, z2)
  float* kk  = ws + 12582912;         // 4194304  (also y1n, h2)
  float* vv  = ws + 16777216;         // 4194304  (also cq, z3)
  float* ao  = ws + 20971520;         // 4194304  (also y2)
  float* y1  = ws + 25165824;         // 4194304
  float* h1c = ws + 29360128;         // 4194304  (FFN hidden chunk 2048x2048)
  float* tn  = ws + 33554432;         // 2097152
  float* ck  = ws + 35651584;         // 2097152
  float* cv  = ws + 37748736;         // 2097152
  float* sn  = ws + 39845888;         // 1048576
  float* sk  = ws + 40894464;         // 1048576
  float* sv  = ws + 41943040;         // 1048576
  float* xc  = ws + 42991616;         // 1048576
  float* att = ws + 44040192;         // 262144
  float* xfp = ws + 44302336;         // 2048
  float* sy  = ws + 44304384;         // 4096
  // total: 44,308,480 floats = 177.2 MB

  dim3 blk(256);
  auto grid = [](int M, int N) { return dim3((unsigned)((N + 127) >> 7), (unsigned)((M + 127) >> 7)); };

  // ---- text/audio cross-attn inputs (independent of main path) ----
  gemm_k<0><<<grid(8, 256), blk, 0, stream>>>(xf, ca_apw, ca_apb, nullptr, 0.f, xfp, 8, 256, 768);
  build_xc_k<<<dim3(4096), blk, 0, stream>>>(xw, xfp, xc);
  gemm_k<0><<<grid(4096, 512), blk, 0, stream>>>(xc, ca_atw, ca_atb, nullptr, 0.f, tn, 4096, 512, 256);
  ln_k<<<dim3(1024), blk, 0, stream>>>(tn, ca_tng, ca_tnb, tn, 4096, 0);
  ln_k<<<dim3(512), blk, 0, stream>>>(xs, ca_sng, ca_snb, sn, 2048, 0);

  // ---- feat_proj + self-attention block ----
  gemm_k<0><<<grid(8192, 512), blk, 0, stream>>>(x, fp_w, fp_b, x, 1.f, xp, 8192, 512, 512);
  ln_k<<<dim3(2048), blk, 0, stream>>>(xp, sa_ng, sa_nb, xn, 8192, 0);
  gemm_k<0><<<grid(8192, 512), blk, 0, stream>>>(xn, sa_qw, sa_qb, nullptr, 0.f, q, 8192, 512, 512);
  gemm_k<0><<<grid(8192, 512), blk, 0, stream>>>(xn, sa_kw, sa_kb, nullptr, 0.f, kk, 8192, 512, 512);
  gemm_k<0><<<grid(8192, 512), blk, 0, stream>>>(xn, sa_vw, sa_vb, nullptr, 0.f, vv, 8192, 512, 512);
  attn_k<<<dim3(256), blk, 0, stream>>>(q, kk, vv, ao);                 // ao = silu(attn_out)
  gemm_k<0><<<grid(8192, 512), blk, 0, stream>>>(ao, sa_ow, sa_ob, xp, 2.f, q, 8192, 512, 512); // z1
  ln_k<<<dim3(2048), blk, 0, stream>>>(q, an_g, an_b, y1, 8192, 0);

  // ---- cross-attention block ----
  ln_k<<<dim3(2048), blk, 0, stream>>>(y1, ca_ng, ca_nb, kk, 8192, 0);  // y1n
  gemm_k<0><<<grid(8192, 512), blk, 0, stream>>>(kk, ca_qw, ca_qb, nullptr, 0.f, vv, 8192, 512, 512); // cq_raw
  softmax64_k<<<dim3(16384), blk, 0, stream>>>(vv, 65536);              // cq
  gemm_k<0><<<grid(4096, 512), blk, 0, stream>>>(tn, ca_kw, ca_kb, nullptr, 0.f, ck, 4096, 512, 512);
  gemm_k<0><<<grid(2048, 512), blk, 0, stream>>>(sn, ca_kw, ca_kb, nullptr, 0.f, sk, 2048, 512, 512);
  gemm_k<0><<<grid(4096, 512), blk, 0, stream>>>(tn, ca_vw, ca_vb, nullptr, 0.f, cv, 4096, 512, 512);
  gemm_k<0><<<grid(2048, 512), blk, 0, stream>>>(sn, ca_vw, ca_vb, nullptr, 0.f, sv, 2048, 512, 512);
  softmax_seq_k<<<dim3(16), blk, 0, stream>>>(ck, 512);
  softmax_seq_k<<<dim3(16), blk, 0, stream>>>(sk, 256);
  attmat_k<<<dim3(64), blk, 0, stream>>>(ck, cv, att, 512);
  sy_k<<<dim3(64), dim3(64), 0, stream>>>(sk, sv, sy);
  cy_k<<<dim3(1024), blk, 0, stream>>>(vv, att, sy, xn);                // xn = silu(cy+sy)
  gemm_k<0><<<grid(8192, 512), blk, 0, stream>>>(xn, ca_ow, ca_ob, y1, 2.f, q, 8192, 512, 512); // z2
  ln_k<<<dim3(2048), blk, 0, stream>>>(q, an_g, an_b, ao, 8192, 0);     // y2

  // ---- FFN block (M-chunked hidden) ----
  for (int mc = 0; mc < 4; ++mc) {
    gemm_k<1><<<grid(2048, 2048), blk, 0, stream>>>(ao + (size_t)mc * 2048 * 512, ffn_w1, ffn_b1,
                                                    nullptr, 0.f, h1c, 2048, 2048, 512);
    gemm_k<0><<<grid(2048, 512), blk, 0, stream>>>(h1c, ffn_w2, ffn_b2, nullptr, 0.f,
                                                   kk + (size_t)mc * 2048 * 512, 2048, 512, 2048);
  }
  ln_k<<<dim3(2048), blk, 0, stream>>>(kk, ffn_ng, ffn_nb, kk, 8192, 1);  // h2 -> silu(LN(h2))
  gemm_k<0><<<grid(8192, 512), blk, 0, stream>>>(kk, ffn_ow, ffn_ob, ao, 2.f, vv, 8192, 512, 512); // z3
  ln_k<<<dim3(2048), blk, 0, stream>>>(vv, an_g, an_b, (float*)d_out, 8192, 0); // y3
}

// Round 3
// 1262.901 us; speedup vs baseline: 3.2030x; 3.2030x over previous
//
#include <hip/hip_runtime.h>
#include <math.h>

typedef unsigned short u16;
typedef short s16x8 __attribute__((ext_vector_type(8)));
typedef float f32x4 __attribute__((ext_vector_type(4)));
typedef unsigned short u16x8 __attribute__((ext_vector_type(8)));
typedef unsigned short u16x4 __attribute__((ext_vector_type(4)));

#define DD 512

__device__ __forceinline__ float silu_f(float x) { return x / (1.f + __expf(-x)); }
__device__ __forceinline__ float gelu_f(float x) { return 0.5f * x * (1.f + erff(x * 0.7071067811865475f)); }
__device__ __forceinline__ u16 f2bf(float f) {
  unsigned u = __float_as_uint(f);
  return (u16)((u + 0x7fffu + ((u >> 16) & 1u)) >> 16);
}
__device__ __forceinline__ float bf2f(u16 u) { return __uint_as_float(((unsigned)u) << 16); }

__device__ __forceinline__ void gload16(const void* g, void* l) {
  __builtin_amdgcn_global_load_lds(
      (const __attribute__((address_space(1))) void*)(g),
      (__attribute__((address_space(3))) void*)(l), 16, 0, 0);
}

// ---------------- bf16 MFMA GEMM: C[M,N] = act(A[M,K]@W[K,N] + bias) + res_scale*res ----------------
// A: [M,K] bf16 row-major. Bt: [N,K] bf16 row-major (W transposed). M%128==0, N%128==0, K%32==0.
// ACT: 0 none, 1 exact GELU. OBF: 1 -> bf16 out (outb), 0 -> fp32 out (outf).
template<int ACT, int OBF>
__global__ __launch_bounds__(256) void gemm_bf(
    const u16* __restrict__ A, const u16* __restrict__ Bt,
    const float* __restrict__ bias, const float* __restrict__ res, float res_scale,
    float* __restrict__ outf, u16* __restrict__ outb, int M, int N, int K)
{
  __shared__ u16 As[128 * 32];
  __shared__ u16 Bs[128 * 32];
  const int t = threadIdx.x, l = t & 63, w = t >> 6;
  const int bm = blockIdx.y << 7, bn = blockIdx.x << 7;
  const int wr = (w >> 1) << 6, wc = (w & 1) << 6;
  f32x4 acc[4][4];
#pragma unroll
  for (int i = 0; i < 4; ++i)
#pragma unroll
    for (int j = 0; j < 4; ++j) acc[i][j] = (f32x4){0.f, 0.f, 0.f, 0.f};

  auto stage = [&](int k0) {
#pragma unroll
    for (int i = 0; i < 2; ++i) {
      int c = t + (i << 8);
      int row = c >> 2, kq = (c & 3) << 3;
      gload16(A + (size_t)(bm + row) * K + k0 + kq, (char*)As + ((w + (i << 2)) << 10));
      gload16(Bt + (size_t)(bn + row) * K + k0 + kq, (char*)Bs + ((w + (i << 2)) << 10));
    }
  };
  stage(0);
  const int fr = l & 15, fk = (l >> 4) << 3;
  for (int k0 = 0;; k0 += 32) {
    __syncthreads();   // staged tile visible (barrier drains vmcnt)
    s16x8 af[4], bg[4];
#pragma unroll
    for (int i = 0; i < 4; ++i) {
      af[i] = *(const s16x8*)&As[(wr + i * 16 + fr) * 32 + fk];
      bg[i] = *(const s16x8*)&Bs[(wc + i * 16 + fr) * 32 + fk];
    }
    __syncthreads();   // all waves done reading LDS
    if (k0 + 32 < K) stage(k0 + 32);
#pragma unroll
    for (int mi = 0; mi < 4; ++mi)
#pragma unroll
      for (int ni = 0; ni < 4; ++ni)
        acc[mi][ni] = __builtin_amdgcn_mfma_f32_16x16x32_bf16(af[mi], bg[ni], acc[mi][ni], 0, 0, 0);
    if (k0 + 32 >= K) break;
  }
  // epilogue: C/D layout col = lane&15, row = (lane>>4)*4 + r
  const int cr0 = (l >> 4) << 2, cc = l & 15;
#pragma unroll
  for (int ni = 0; ni < 4; ++ni) {
    int n = bn + wc + ni * 16 + cc;
    float bia = bias[n];
#pragma unroll
    for (int mi = 0; mi < 4; ++mi) {
#pragma unroll
      for (int r = 0; r < 4; ++r) {
        int m = bm + wr + mi * 16 + cr0 + r;
        size_t off = (size_t)m * N + n;
        float o = acc[mi][ni][r] + bia;
        if (ACT == 1) o = gelu_f(o);
        if (res) o = fmaf(res_scale, res[off], o);
        if (OBF) outb[off] = f2bf(o);
        else outf[off] = o;
      }
    }
  }
}

// ---------------- fp32 GEMM (only for tiny xf projection, M=8) ----------------
__global__ __launch_bounds__(256) void gemm32_k(
    const float* __restrict__ A, const float* __restrict__ W,
    const float* __restrict__ bias, float* __restrict__ C, int M, int N, int K)
{
  __shared__ float As[16][132];
  __shared__ float Bs[16][132];
  const int tid = threadIdx.x;
  const int tx = tid & 15, ty = tid >> 4;
  const int bm = blockIdx.y << 7, bn = blockIdx.x << 7;
  float acc[8][8];
#pragma unroll
  for (int i = 0; i < 8; ++i)
#pragma unroll
    for (int j = 0; j < 8; ++j) acc[i][j] = 0.f;
  for (int k0 = 0; k0 < K; k0 += 16) {
    __syncthreads();
#pragma unroll
    for (int i = 0; i < 2; ++i) {
      int f = tid + (i << 8);
      int row = f >> 2, c4 = (f & 3) << 2;
      float4 a4 = make_float4(0.f, 0.f, 0.f, 0.f);
      if (bm + row < M) a4 = *(const float4*)(A + (size_t)(bm + row) * K + k0 + c4);
      As[c4 + 0][row] = a4.x; As[c4 + 1][row] = a4.y;
      As[c4 + 2][row] = a4.z; As[c4 + 3][row] = a4.w;
    }
#pragma unroll
    for (int i = 0; i < 2; ++i) {
      int f = tid + (i << 8);
      int row = f >> 5, c4 = (f & 31) << 2;
      *(float4*)&Bs[row][c4] = *(const float4*)(W + (size_t)(k0 + row) * N + bn + c4);
    }
    __syncthreads();
#pragma unroll
    for (int kk = 0; kk < 16; ++kk) {
      float a[8], b[8];
      *(float4*)&a[0] = *(float4*)&As[kk][ty * 8];
      *(float4*)&a[4] = *(float4*)&As[kk][ty * 8 + 4];
      *(float4*)&b[0] = *(float4*)&Bs[kk][tx * 8];
      *(float4*)&b[4] = *(float4*)&Bs[kk][tx * 8 + 4];
#pragma unroll
      for (int i = 0; i < 8; ++i)
#pragma unroll
        for (int j = 0; j < 8; ++j) acc[i][j] = fmaf(a[i], b[j], acc[i][j]);
    }
  }
#pragma unroll
  for (int i = 0; i < 8; ++i) {
    int m = bm + ty * 8 + i;
    if (m < M) {
#pragma unroll
      for (int j4 = 0; j4 < 2; ++j4) {
        int n = bn + tx * 8 + j4 * 4;
        float4 bi = *(const float4*)(bias + n);
        float4 o;
        o.x = acc[i][j4 * 4 + 0] + bi.x; o.y = acc[i][j4 * 4 + 1] + bi.y;
        o.z = acc[i][j4 * 4 + 2] + bi.z; o.w = acc[i][j4 * 4 + 3] + bi.w;
        *(float4*)(C + (size_t)m * N + n) = o;
      }
    }
  }
}

// ---------------- LayerNorm over D=512, dual fp32/bf16 out, optional fused SiLU ----------------
__global__ __launch_bounds__(256) void ln_k(
    const float* __restrict__ src, const float* __restrict__ g,
    const float* __restrict__ b, float* __restrict__ out32, u16* __restrict__ out16,
    int rows, int do_silu)
{
  int lane = threadIdx.x & 63, wv = threadIdx.x >> 6;
  int row = (blockIdx.x << 2) + wv;
  if (row >= rows) return;
  const float* p = src + (size_t)row * DD;
  float4 v0 = *(const float4*)(p + lane * 4);
  float4 v1 = *(const float4*)(p + 256 + lane * 4);
  float s = v0.x + v0.y + v0.z + v0.w + v1.x + v1.y + v1.z + v1.w;
  float ss = v0.x*v0.x + v0.y*v0.y + v0.z*v0.z + v0.w*v0.w
           + v1.x*v1.x + v1.y*v1.y + v1.z*v1.z + v1.w*v1.w;
#pragma unroll
  for (int m = 1; m < 64; m <<= 1) { s += __shfl_xor(s, m); ss += __shfl_xor(ss, m); }
  float mean = s * (1.f / 512.f);
  float var = ss * (1.f / 512.f) - mean * mean;
  float rstd = rsqrtf(var + 1e-5f);
  float4 g0 = *(const float4*)(g + lane * 4);
  float4 g1 = *(const float4*)(g + 256 + lane * 4);
  float4 b0 = *(const float4*)(b + lane * 4);
  float4 b1 = *(const float4*)(b + 256 + lane * 4);
  float o[8];
  o[0] = (v0.x - mean) * rstd * g0.x + b0.x;
  o[1] = (v0.y - mean) * rstd * g0.y + b0.y;
  o[2] = (v0.z - mean) * rstd * g0.z + b0.z;
  o[3] = (v0.w - mean) * rstd * g0.w + b0.w;
  o[4] = (v1.x - mean) * rstd * g1.x + b1.x;
  o[5] = (v1.y - mean) * rstd * g1.y + b1.y;
  o[6] = (v1.z - mean) * rstd * g1.z + b1.z;
  o[7] = (v1.w - mean) * rstd * g1.w + b1.w;
  if (do_silu) {
#pragma unroll
    for (int j = 0; j < 8; ++j) o[j] = silu_f(o[j]);
  }
  if (out32) {
    *(float4*)(out32 + (size_t)row * DD + lane * 4) = make_float4(o[0], o[1], o[2], o[3]);
    *(float4*)(out32 + (size_t)row * DD + 256 + lane * 4) = make_float4(o[4], o[5], o[6], o[7]);
  }
  if (out16) {
    u16x4 h0, h1;
#pragma unroll
    for (int j = 0; j < 4; ++j) { h0[j] = f2bf(o[j]); h1[j] = f2bf(o[4 + j]); }
    *(u16x4*)(out16 + (size_t)row * DD + lane * 4) = h0;
    *(u16x4*)(out16 + (size_t)row * DD + 256 + lane * 4) = h1;
  }
}

// ---------------- self-attention: 4 threads per query row (16 dh dims each), bf16 I/O ----------------
// grid = B*H*16 (64 queries/block), out = silu(attn) bf16
__global__ __launch_bounds__(256) void attn2_k(
    const u16* __restrict__ q, const u16* __restrict__ k,
    const u16* __restrict__ v, u16* __restrict__ out)
{
  __shared__ float Ks[64 * 64];
  __shared__ float Vs[64 * 64];
  int blk = blockIdx.x;
  int tc = blk & 15, h = (blk >> 4) & 7, b = blk >> 7;
  int t = threadIdx.x;
  int qi = t >> 2, part = t & 3;
  int qrow = (tc << 6) + qi;
  size_t qoff = ((size_t)(b * 1024 + qrow)) * DD + h * 64 + part * 16;
  const u16* qp = q + qoff;
  u16x8 q0 = *(const u16x8*)qp;
  u16x8 q1 = *(const u16x8*)(qp + 8);
  float qr[16];
#pragma unroll
  for (int j = 0; j < 8; ++j) { qr[j] = bf2f(q0[j]); qr[8 + j] = bf2f(q1[j]); }
  float acc[16];
#pragma unroll
  for (int j = 0; j < 16; ++j) acc[j] = 0.f;
  float lsum = 0.f;
  int srow = t >> 2, scol = (t & 3) << 4;
  for (int st = 0; st < 16; ++st) {
    __syncthreads();
    size_t src = ((size_t)(b * 1024 + (st << 6) + srow)) * DD + h * 64 + scol;
    u16x8 a0 = *(const u16x8*)(k + src), a1 = *(const u16x8*)(k + src + 8);
    u16x8 c0 = *(const u16x8*)(v + src), c1 = *(const u16x8*)(v + src + 8);
    float* kd = &Ks[srow * 64 + scol];
    float* vd = &Vs[srow * 64 + scol];
#pragma unroll
    for (int j = 0; j < 8; ++j) {
      kd[j] = bf2f(a0[j]); kd[8 + j] = bf2f(a1[j]);
      vd[j] = bf2f(c0[j]); vd[8 + j] = bf2f(c1[j]);
    }
    __syncthreads();
    for (int ss = 0; ss < 64; ++ss) {
      const float* kr = &Ks[ss * 64 + part * 16];
      float sc = 0.f;
#pragma unroll
      for (int j = 0; j < 16; ++j) sc = fmaf(qr[j], kr[j], sc);
      sc += __shfl_xor(sc, 1);
      sc += __shfl_xor(sc, 2);
      float e = __expf(sc * 0.125f);
      lsum += e;
      const float* vr = &Vs[ss * 64 + part * 16];
#pragma unroll
      for (int j = 0; j < 16; ++j) acc[j] = fmaf(e, vr[j], acc[j]);
    }
  }
  float inv = 1.f / lsum;
  u16x8 o0, o1;
#pragma unroll
  for (int j = 0; j < 8; ++j) {
    o0[j] = f2bf(silu_f(acc[j] * inv));
    o1[j] = f2bf(silu_f(acc[8 + j] * inv));
  }
  u16* op = out + qoff;
  *(u16x8*)op = o0;
  *(u16x8*)(op + 8) = o1;
}

// ---------------- softmax over contiguous rows of 64 (cq), in-place fp32 ----------------
__global__ __launch_bounds__(256) void softmax64_k(float* __restrict__ p, int rows)
{
  int lane = threadIdx.x & 63, wv = threadIdx.x >> 6;
  int row = (blockIdx.x << 2) + wv;
  if (row >= rows) return;
  float x = p[(size_t)row * 64 + lane];
  float m = x;
#pragma unroll
  for (int mk = 1; mk < 64; mk <<= 1) m = fmaxf(m, __shfl_xor(m, mk));
  float e = __expf(x - m);
  float s = e;
#pragma unroll
  for (int mk = 1; mk < 64; mk <<= 1) s += __shfl_xor(s, mk);
  p[(size_t)row * 64 + lane] = e / s;
}

// ---------------- softmax over sequence axis (stride 512), in-place ----------------
__global__ __launch_bounds__(256) void softmax_seq_k(float* __restrict__ p, int nlen)
{
  int b = blockIdx.x >> 1;
  int c = ((blockIdx.x & 1) << 8) + threadIdx.x;
  float* base = p + (size_t)b * nlen * DD + c;
  float m = -1e30f;
  for (int n = 0; n < nlen; ++n) m = fmaxf(m, base[(size_t)n * DD]);
  float s = 0.f;
  for (int n = 0; n < nlen; ++n) s += __expf(base[(size_t)n * DD] - m);
  float inv = 1.f / s;
  for (int n = 0; n < nlen; ++n) base[(size_t)n * DD] = __expf(base[(size_t)n * DD] - m) * inv;
}

// ---------------- build concat([xw, broadcast(xf_p)]) -> bf16 [B,512,256] ----------------
__global__ __launch_bounds__(256) void build_xc_k(
    const float* __restrict__ xw, const float* __restrict__ xfp, u16* __restrict__ xc)
{
  int idx = blockIdx.x * 256 + threadIdx.x;
  int c = idx & 255, n = (idx >> 8) & 511, b = idx >> 17;
  float val = (n < 256) ? xw[((b << 8) + n) * 256 + c] : xfp[(b << 8) + c];
  xc[idx] = f2bf(val);
}

// ---------------- att[b,h,d,l] = sum_n ck[b,n,h,d]*cv[b,n,h,l] ; grid = B*H ----------------
__global__ __launch_bounds__(256) void attmat_k(
    const float* __restrict__ ckp, const float* __restrict__ cvp,
    float* __restrict__ att, int nlen)
{
  __shared__ float a_s[64][68];
  __shared__ float b_s[64][68];
  int h = blockIdx.x & 7, b = blockIdx.x >> 3;
  int tid = threadIdx.x;
  int d = tid & 63, lg = tid >> 6;
  float acc[16];
#pragma unroll
  for (int j = 0; j < 16; ++j) acc[j] = 0.f;
  for (int n0 = 0; n0 < nlen; n0 += 64) {
    __syncthreads();
#pragma unroll
    for (int i = 0; i < 4; ++i) {
      int f = tid + (i << 8);
      int row = f >> 4, c4 = (f & 15) << 2;
      size_t src = ((size_t)(b * nlen + n0 + row)) * DD + h * 64 + c4;
      *(float4*)&a_s[row][c4] = *(const float4*)(ckp + src);
      *(float4*)&b_s[row][c4] = *(const float4*)(cvp + src);
    }
    __syncthreads();
    for (int nn = 0; nn < 64; ++nn) {
      float av = a_s[nn][d];
#pragma unroll
      for (int j4 = 0; j4 < 4; ++j4) {
        float4 b4 = *(float4*)&b_s[nn][lg * 16 + j4 * 4];
        acc[j4*4+0] = fmaf(av, b4.x, acc[j4*4+0]);
        acc[j4*4+1] = fmaf(av, b4.y, acc[j4*4+1]);
        acc[j4*4+2] = fmaf(av, b4.z, acc[j4*4+2]);
        acc[j4*4+3] = fmaf(av, b4.w, acc[j4*4+3]);
      }
    }
  }
  float* op = att + (size_t)(b * 8 + h) * 4096 + d * 64 + lg * 16;
#pragma unroll
  for (int j4 = 0; j4 < 4; ++j4)
    *(float4*)(op + j4 * 4) = make_float4(acc[j4*4+0], acc[j4*4+1], acc[j4*4+2], acc[j4*4+3]);
}

// ---------------- sy[b,h,l] = sum_s (sum_d sk[b,s,h,d]) * sv[b,s,h,l] ----------------
__global__ __launch_bounds__(64) void sy_k(
    const float* __restrict__ skp, const float* __restrict__ svp, float* __restrict__ sy)
{
  int h = blockIdx.x & 7, b = blockIdx.x >> 3;
  int lane = threadIdx.x;
  float acc = 0.f;
  for (int s = 0; s < 256; ++s) {
    size_t base = ((size_t)(b * 256 + s)) * DD + h * 64 + lane;
    float w = skp[base];
#pragma unroll
    for (int m = 1; m < 64; m <<= 1) w += __shfl_xor(w, m);
    acc = fmaf(w, svp[base], acc);
  }
  sy[(b * 8 + h) * 64 + lane] = acc;
}

// ---------------- out = silu(cq @ att + sy) bf16 ; grid = B*H*16 ----------------
__global__ __launch_bounds__(256) void cy_k(
    const float* __restrict__ cq, const float* __restrict__ att,
    const float* __restrict__ sy, u16* __restrict__ out)
{
  __shared__ float atts[64][68];
  __shared__ float qs[64][68];
  __shared__ float sys[64];
  int blk = blockIdx.x;
  int tt = blk & 15, h = (blk >> 4) & 7, b = blk >> 7;
  int t0 = tt << 6;
  int tid = threadIdx.x;
#pragma unroll
  for (int i = 0; i < 4; ++i) {
    int f = tid + (i << 8);
    int row = f >> 4, c4 = (f & 15) << 2;
    *(float4*)&atts[row][c4] = *(const float4*)(att + (size_t)(b * 8 + h) * 4096 + row * 64 + c4);
    *(float4*)&qs[row][c4] = *(const float4*)(cq + ((size_t)(b * 1024 + t0 + row)) * DD + h * 64 + c4);
  }
  if (tid < 64) sys[tid] = sy[(b * 8 + h) * 64 + tid];
  __syncthreads();
  int r = tid >> 2, lg = tid & 3;
  float acc[16];
#pragma unroll
  for (int j = 0; j < 16; ++j) acc[j] = 0.f;
  for (int d = 0; d < 64; ++d) {
    float qv = qs[r][d];
#pragma unroll
    for (int j4 = 0; j4 < 4; ++j4) {
      float4 a4 = *(float4*)&atts[d][lg * 16 + j4 * 4];
      acc[j4*4+0] = fmaf(qv, a4.x, acc[j4*4+0]);
      acc[j4*4+1] = fmaf(qv, a4.y, acc[j4*4+1]);
      acc[j4*4+2] = fmaf(qv, a4.z, acc[j4*4+2]);
      acc[j4*4+3] = fmaf(qv, a4.w, acc[j4*4+3]);
    }
  }
  u16* op = out + ((size_t)(b * 1024 + t0 + r)) * DD + h * 64 + lg * 16;
#pragma unroll
  for (int j4 = 0; j4 < 4; ++j4) {
    u16x4 o4;
    o4[0] = f2bf(silu_f(acc[j4*4+0] + sys[lg * 16 + j4*4+0]));
    o4[1] = f2bf(silu_f(acc[j4*4+1] + sys[lg * 16 + j4*4+1]));
    o4[2] = f2bf(silu_f(acc[j4*4+2] + sys[lg * 16 + j4*4+2]));
    o4[3] = f2bf(silu_f(acc[j4*4+3] + sys[lg * 16 + j4*4+3]));
    *(u16x4*)(op + j4 * 4) = o4;
  }
}

// ---------------- fp32 -> bf16 elementwise convert ----------------
__global__ __launch_bounds__(256) void cvtf2b_k(const float* __restrict__ in, u16* __restrict__ out, int n)
{
  int i = (blockIdx.x * 256 + threadIdx.x) * 4;
  if (i >= n) return;
  float4 v = *(const float4*)(in + i);
  u16x4 o;
  o[0] = f2bf(v.x); o[1] = f2bf(v.y); o[2] = f2bf(v.z); o[3] = f2bf(v.w);
  *(u16x4*)(out + i) = o;
}

// ---------------- W[K][N] fp32 -> Wt[N][K] bf16 (tiled transpose) ----------------
__global__ __launch_bounds__(256) void wtrans_k(const float* __restrict__ W, u16* __restrict__ Wt, int Kd, int Nd)
{
  __shared__ float tile[32][33];
  int ntn = Nd >> 5;
  int tk = blockIdx.x / ntn, tn = blockIdx.x % ntn;
  int lx = threadIdx.x & 31, ly = threadIdx.x >> 5;
#pragma unroll
  for (int i = 0; i < 4; ++i)
    tile[ly + 8 * i][lx] = W[(size_t)(tk * 32 + ly + 8 * i) * Nd + tn * 32 + lx];
  __syncthreads();
#pragma unroll
  for (int i = 0; i < 4; ++i)
    Wt[(size_t)(tn * 32 + ly + 8 * i) * Kd + tk * 32 + lx] = f2bf(tile[lx][ly + 8 * i]);
}

extern "C" void kernel_launch(void* const* d_in, const int* in_sizes, int n_in,
                              void* d_out, int out_size, void* d_ws, size_t ws_size,
                              hipStream_t stream)
{
  const float* x      = (const float*)d_in[0];
  const float* xf     = (const float*)d_in[1];
  const float* xw     = (const float*)d_in[2];
  const float* xs     = (const float*)d_in[3];
  const float* fp_w   = (const float*)d_in[4];
  const float* fp_b   = (const float*)d_in[5];
  const float* sa_ng  = (const float*)d_in[6];
  const float* sa_nb  = (const float*)d_in[7];
  const float* sa_qw  = (const float*)d_in[8];
  const float* sa_qb  = (const float*)d_in[9];
  const float* sa_kw  = (const float*)d_in[10];
  const float* sa_kb  = (const float*)d_in[11];
  const float* sa_vw  = (const float*)d_in[12];
  const float* sa_vb  = (const float*)d_in[13];
  const float* sa_ow  = (const float*)d_in[14];
  const float* sa_ob  = (const float*)d_in[15];
  const float* ca_ng  = (const float*)d_in[16];
  const float* ca_nb  = (const float*)d_in[17];
  const float* ca_tng = (const float*)d_in[18];
  const float* ca_tnb = (const float*)d_in[19];
  const float* ca_sng = (const float*)d_in[20];
  const float* ca_snb = (const float*)d_in[21];
  const float* ca_qw  = (const float*)d_in[22];
  const float* ca_qb  = (const float*)d_in[23];
  const float* ca_kw  = (const float*)d_in[24];
  const float* ca_kb  = (const float*)d_in[25];
  const float* ca_vw  = (const float*)d_in[26];
  const float* ca_vb  = (const float*)d_in[27];
  const float* ca_apw = (const float*)d_in[28];
  const float* ca_apb = (const float*)d_in[29];
  const float* ca_atw = (const float*)d_in[30];
  const float* ca_atb = (const float*)d_in[31];
  const float* ca_ow  = (const float*)d_in[32];
  const float* ca_ob  = (const float*)d_in[33];
  const float* an_g   = (const float*)d_in[34];
  const float* an_b   = (const float*)d_in[35];
  const float* ffn_w1 = (const float*)d_in[36];
  const float* ffn_b1 = (const float*)d_in[37];
  const float* ffn_w2 = (const float*)d_in[38];
  const float* ffn_b2 = (const float*)d_in[39];
  const float* ffn_ng = (const float*)d_in[40];
  const float* ffn_nb = (const float*)d_in[41];
  const float* ffn_ow = (const float*)d_in[42];
  const float* ffn_ob = (const float*)d_in[43];

  float* ws = (float*)d_ws;
  // fp32 slots (reused sequentially)
  float* slotZ = ws;                       // z1 -> cq -> z2 -> h2 -> z3   (4M f)
  float* slotP = ws + 4194304;             // xp -> y1 -> y2               (4M f)
  // bf16 slots (2M floats = 4M bf16 each)
  u16* S1 = (u16*)(ws + 8388608);          // xbf -> y1n -> hsb
  u16* S2 = (u16*)(ws + 10485760);         // xn  -> cys
  u16* S3 = (u16*)(ws + 12582912);         // qb  -> y2b
  u16* S4 = (u16*)(ws + 14680064);         // kb
  u16* S5 = (u16*)(ws + 16777216);         // vb
  u16* S6 = (u16*)(ws + 18874368);         // ao
  // overlay region: ck/cv/sk/sv/tnr (fp32) then h1 (bf16) aliases it
  float* ck  = ws + 20971520;              // 2M f
  float* cv  = ws + 23068672;              // 2M f
  float* sk  = ws + 25165824;              // 1M f
  float* sv  = ws + 26214400;              // 1M f
  float* tnr = ws + 27262976;              // 2M f
  u16* tn = (u16*)(ws + 29360128);         // 2M bf16
  u16* sn = (u16*)(ws + 30408704);         // 1M bf16
  u16* h1 = (u16*)(ws + 20971520);         // 16M bf16, aliases ck..tnr (dead by then)
  u16* xc = (u16*)(ws + 30932992);         // 1M bf16
  float* att = ws + 31457280;              // 256K f
  float* xfp = ws + 31719424;              // 2K f
  float* sy  = ws + 31723520;              // 4K f
  u16* wb = (u16*)(ws + 31727616);         // weights bf16 pool
  u16* fp_wt   = wb;
  u16* sa_qwt  = wb + 262144;
  u16* sa_kwt  = wb + 524288;
  u16* sa_vwt  = wb + 786432;
  u16* sa_owt  = wb + 1048576;
  u16* ca_qwt  = wb + 1310720;
  u16* ca_kwt  = wb + 1572864;
  u16* ca_vwt  = wb + 1835008;
  u16* ca_owt  = wb + 2097152;
  u16* ffn_owt = wb + 2359296;
  u16* ca_atwt = wb + 2621440;             // [512][256]
  u16* ffn_w1t = wb + 2752512;             // [2048][512]
  u16* ffn_w2t = wb + 3801088;             // [512][2048]

  dim3 blk(256);
  auto bgrid = [](int M, int N) { return dim3((unsigned)(N >> 7), (unsigned)(M >> 7)); };

  // ---- conversions ----
  cvtf2b_k<<<dim3(4096), blk, 0, stream>>>(x, S1, 4194304);
  wtrans_k<<<dim3(256), blk, 0, stream>>>(fp_w,   fp_wt,   512, 512);
  wtrans_k<<<dim3(256), blk, 0, stream>>>(sa_qw,  sa_qwt,  512, 512);
  wtrans_k<<<dim3(256), blk, 0, stream>>>(sa_kw,  sa_kwt,  512, 512);
  wtrans_k<<<dim3(256), blk, 0, stream>>>(sa_vw,  sa_vwt,  512, 512);
  wtrans_k<<<dim3(256), blk, 0, stream>>>(sa_ow,  sa_owt,  512, 512);
  wtrans_k<<<dim3(256), blk, 0, stream>>>(ca_qw,  ca_qwt,  512, 512);
  wtrans_k<<<dim3(256), blk, 0, stream>>>(ca_kw,  ca_kwt,  512, 512);
  wtrans_k<<<dim3(256), blk, 0, stream>>>(ca_vw,  ca_vwt,  512, 512);
  wtrans_k<<<dim3(256), blk, 0, stream>>>(ca_ow,  ca_owt,  512, 512);
  wtrans_k<<<dim3(256), blk, 0, stream>>>(ffn_ow, ffn_owt, 512, 512);
  wtrans_k<<<dim3(128), blk, 0, stream>>>(ca_atw, ca_atwt, 256, 512);
  wtrans_k<<<dim3(1024), blk, 0, stream>>>(ffn_w1, ffn_w1t, 512, 2048);
  wtrans_k<<<dim3(1024), blk, 0, stream>>>(ffn_w2, ffn_w2t, 2048, 512);

  // ---- text/audio cross-attn inputs ----
  gemm32_k<<<dim3(2, 1), blk, 0, stream>>>(xf, ca_apw, ca_apb, xfp, 8, 256, 768);
  build_xc_k<<<dim3(4096), blk, 0, stream>>>(xw, xfp, xc);
  gemm_bf<0,0><<<bgrid(4096, 512), blk, 0, stream>>>(xc, ca_atwt, ca_atb, nullptr, 0.f, tnr, nullptr, 4096, 512, 256);
  ln_k<<<dim3(1024), blk, 0, stream>>>(tnr, ca_tng, ca_tnb, nullptr, tn, 4096, 0);
  ln_k<<<dim3(512), blk, 0, stream>>>(xs, ca_sng, ca_snb, nullptr, sn, 2048, 0);

  // ---- feat_proj + self-attention ----
  gemm_bf<0,0><<<bgrid(8192, 512), blk, 0, stream>>>(S1, fp_wt, fp_b, x, 1.f, slotP, nullptr, 8192, 512, 512); // xp
  ln_k<<<dim3(2048), blk, 0, stream>>>(slotP, sa_ng, sa_nb, nullptr, S2, 8192, 0);                             // xn
  gemm_bf<0,1><<<bgrid(8192, 512), blk, 0, stream>>>(S2, sa_qwt, sa_qb, nullptr, 0.f, nullptr, S3, 8192, 512, 512);
  gemm_bf<0,1><<<bgrid(8192, 512), blk, 0, stream>>>(S2, sa_kwt, sa_kb, nullptr, 0.f, nullptr, S4, 8192, 512, 512);
  gemm_bf<0,1><<<bgrid(8192, 512), blk, 0, stream>>>(S2, sa_vwt, sa_vb, nullptr, 0.f, nullptr, S5, 8192, 512, 512);
  attn2_k<<<dim3(1024), blk, 0, stream>>>(S3, S4, S5, S6);                                                     // ao=silu(attn)
  gemm_bf<0,0><<<bgrid(8192, 512), blk, 0, stream>>>(S6, sa_owt, sa_ob, slotP, 2.f, slotZ, nullptr, 8192, 512, 512); // z1
  ln_k<<<dim3(2048), blk, 0, stream>>>(slotZ, an_g, an_b, slotP, nullptr, 8192, 0);                            // y1

  // ---- cross-attention ----
  ln_k<<<dim3(2048), blk, 0, stream>>>(slotP, ca_ng, ca_nb, nullptr, S1, 8192, 0);                             // y1n
  gemm_bf<0,0><<<bgrid(8192, 512), blk, 0, stream>>>(S1, ca_qwt, ca_qb, nullptr, 0.f, slotZ, nullptr, 8192, 512, 512); // cq_raw
  softmax64_k<<<dim3(16384), blk, 0, stream>>>(slotZ, 65536);                                                  // cq
  gemm_bf<0,0><<<bgrid(4096, 512), blk, 0, stream>>>(tn, ca_kwt, ca_kb, nullptr, 0.f, ck, nullptr, 4096, 512, 512);
  gemm_bf<0,0><<<bgrid(2048, 512), blk, 0, stream>>>(sn, ca_kwt, ca_kb, nullptr, 0.f, sk, nullptr, 2048, 512, 512);
  gemm_bf<0,0><<<bgrid(4096, 512), blk, 0, stream>>>(tn, ca_vwt, ca_vb, nullptr, 0.f, cv, nullptr, 4096, 512, 512);
  gemm_bf<0,0><<<bgrid(2048, 512), blk, 0, stream>>>(sn, ca_vwt, ca_vb, nullptr, 0.f, sv, nullptr, 2048, 512, 512);
  softmax_seq_k<<<dim3(16), blk, 0, stream>>>(ck, 512);
  softmax_seq_k<<<dim3(16), blk, 0, stream>>>(sk, 256);
  attmat_k<<<dim3(64), blk, 0, stream>>>(ck, cv, att, 512);
  sy_k<<<dim3(64), dim3(64), 0, stream>>>(sk, sv, sy);
  cy_k<<<dim3(1024), blk, 0, stream>>>(slotZ, att, sy, S2);                                                    // cys=silu(cy+sy)
  gemm_bf<0,0><<<bgrid(8192, 512), blk, 0, stream>>>(S2, ca_owt, ca_ob, slotP, 2.f, slotZ, nullptr, 8192, 512, 512); // z2
  ln_k<<<dim3(2048), blk, 0, stream>>>(slotZ, an_g, an_b, slotP, S3, 8192, 0);                                 // y2 (+bf16)

  // ---- FFN ----
  gemm_bf<1,1><<<bgrid(8192, 2048), blk, 0, stream>>>(S3, ffn_w1t, ffn_b1, nullptr, 0.f, nullptr, h1, 8192, 2048, 512);
  gemm_bf<0,0><<<bgrid(8192, 512), blk, 0, stream>>>(h1, ffn_w2t, ffn_b2, nullptr, 0.f, slotZ, nullptr, 8192, 512, 2048); // h2
  ln_k<<<dim3(2048), blk, 0, stream>>>(slotZ, ffn_ng, ffn_nb, nullptr, S1, 8192, 1);                           // silu(LN(h2))
  gemm_bf<0,0><<<bgrid(8192, 512), blk, 0, stream>>>(S1, ffn_owt, ffn_ob, slotP, 2.f, slotZ, nullptr, 8192, 512, 512); // z3
  ln_k<<<dim3(2048), blk, 0, stream>>>(slotZ, an_g, an_b, (float*)d_out, nullptr, 8192, 0);                    // y3
}

// Round 4
// 615.965 us; speedup vs baseline: 6.5670x; 2.0503x over previous
//
#include <hip/hip_runtime.h>
#include <math.h>

typedef unsigned short u16;
typedef short s16x8 __attribute__((ext_vector_type(8)));
typedef float f32x4 __attribute__((ext_vector_type(4)));
typedef unsigned short u16x8 __attribute__((ext_vector_type(8)));
typedef unsigned short u16x4 __attribute__((ext_vector_type(4)));

#define DD 512

__device__ __forceinline__ float silu_f(float x) { return x / (1.f + __expf(-x)); }
__device__ __forceinline__ float gelu_f(float x) { return 0.5f * x * (1.f + erff(x * 0.7071067811865475f)); }
__device__ __forceinline__ u16 f2bf(float f) {
  unsigned u = __float_as_uint(f);
  return (u16)((u + 0x7fffu + ((u >> 16) & 1u)) >> 16);
}
__device__ __forceinline__ float bf2f(u16 u) { return __uint_as_float(((unsigned)u) << 16); }

__device__ __forceinline__ void gload16(const void* g, void* l) {
  __builtin_amdgcn_global_load_lds(
      (const __attribute__((address_space(1))) void*)(g),
      (__attribute__((address_space(3))) void*)(l), 16, 0, 0);
}

// ---------------- bf16 MFMA GEMM: C[M,N] = act(A[M,K]@W[K,N] + bias) + res_scale*res ----------------
// A: [M,K] bf16 row-major. Bt: [N,K] bf16 row-major. M%128==0, N%128==0, K%32==0.
// ACT: 0 none, 1 exact GELU. OB: 0 fp32 out, 1 bf16 out, 2 bf16 attn-transposed out
// (OB==2: N==512 channels = h*64+d, M = b*1024+t; writes outb as Vt[(b*8+h)*64+d][t], row len 1024)
template<int ACT, int OB>
__global__ __launch_bounds__(256) void gemm_bf(
    const u16* __restrict__ A, const u16* __restrict__ Bt,
    const float* __restrict__ bias, const float* __restrict__ res, float res_scale,
    float* __restrict__ outf, u16* __restrict__ outb, int M, int N, int K)
{
  __shared__ u16 As[128 * 32];
  __shared__ u16 Bs[128 * 32];
  const int t = threadIdx.x, l = t & 63, w = t >> 6;
  const int bm = blockIdx.y << 7, bn = blockIdx.x << 7;
  const int wr = (w >> 1) << 6, wc = (w & 1) << 6;
  f32x4 acc[4][4];
#pragma unroll
  for (int i = 0; i < 4; ++i)
#pragma unroll
    for (int j = 0; j < 4; ++j) acc[i][j] = (f32x4){0.f, 0.f, 0.f, 0.f};

  auto stage = [&](int k0) {
#pragma unroll
    for (int i = 0; i < 2; ++i) {
      int c = t + (i << 8);
      int row = c >> 2, kq = (c & 3) << 3;
      gload16(A + (size_t)(bm + row) * K + k0 + kq, (char*)As + ((w + (i << 2)) << 10));
      gload16(Bt + (size_t)(bn + row) * K + k0 + kq, (char*)Bs + ((w + (i << 2)) << 10));
    }
  };
  stage(0);
  const int fr = l & 15, fk = (l >> 4) << 3;
  for (int k0 = 0;; k0 += 32) {
    __syncthreads();
    s16x8 af[4], bg[4];
#pragma unroll
    for (int i = 0; i < 4; ++i) {
      af[i] = *(const s16x8*)&As[(wr + i * 16 + fr) * 32 + fk];
      bg[i] = *(const s16x8*)&Bs[(wc + i * 16 + fr) * 32 + fk];
    }
    __syncthreads();
    if (k0 + 32 < K) stage(k0 + 32);
#pragma unroll
    for (int mi = 0; mi < 4; ++mi)
#pragma unroll
      for (int ni = 0; ni < 4; ++ni)
        acc[mi][ni] = __builtin_amdgcn_mfma_f32_16x16x32_bf16(af[mi], bg[ni], acc[mi][ni], 0, 0, 0);
    if (k0 + 32 >= K) break;
  }
  const int cr0 = (l >> 4) << 2, cc = l & 15;
#pragma unroll
  for (int ni = 0; ni < 4; ++ni) {
    int n = bn + wc + ni * 16 + cc;
    float bia = bias[n];
    if (OB == 2) {
#pragma unroll
      for (int mi = 0; mi < 4; ++mi) {
        int m0 = bm + wr + mi * 16 + cr0;
        u16x4 pk;
#pragma unroll
        for (int r = 0; r < 4; ++r) pk[r] = f2bf(acc[mi][ni][r] + bia);
        size_t rowp = ((size_t)((m0 >> 10) * 8 + (n >> 6))) * 64 + (n & 63);
        *(u16x4*)(outb + rowp * 1024 + (m0 & 1023)) = pk;
      }
    } else {
#pragma unroll
      for (int mi = 0; mi < 4; ++mi) {
#pragma unroll
        for (int r = 0; r < 4; ++r) {
          int m = bm + wr + mi * 16 + cr0 + r;
          size_t off = (size_t)m * N + n;
          float o = acc[mi][ni][r] + bia;
          if (ACT == 1) o = gelu_f(o);
          if (res) o = fmaf(res_scale, res[off], o);
          if (OB == 1) outb[off] = f2bf(o);
          else outf[off] = o;
        }
      }
    }
  }
}

// ---------------- fp32 GEMM (only for tiny xf projection, M=8) ----------------
__global__ __launch_bounds__(256) void gemm32_k(
    const float* __restrict__ A, const float* __restrict__ W,
    const float* __restrict__ bias, float* __restrict__ C, int M, int N, int K)
{
  __shared__ float As[16][132];
  __shared__ float Bs[16][132];
  const int tid = threadIdx.x;
  const int tx = tid & 15, ty = tid >> 4;
  const int bm = blockIdx.y << 7, bn = blockIdx.x << 7;
  float acc[8][8];
#pragma unroll
  for (int i = 0; i < 8; ++i)
#pragma unroll
    for (int j = 0; j < 8; ++j) acc[i][j] = 0.f;
  for (int k0 = 0; k0 < K; k0 += 16) {
    __syncthreads();
#pragma unroll
    for (int i = 0; i < 2; ++i) {
      int f = tid + (i << 8);
      int row = f >> 2, c4 = (f & 3) << 2;
      float4 a4 = make_float4(0.f, 0.f, 0.f, 0.f);
      if (bm + row < M) a4 = *(const float4*)(A + (size_t)(bm + row) * K + k0 + c4);
      As[c4 + 0][row] = a4.x; As[c4 + 1][row] = a4.y;
      As[c4 + 2][row] = a4.z; As[c4 + 3][row] = a4.w;
    }
#pragma unroll
    for (int i = 0; i < 2; ++i) {
      int f = tid + (i << 8);
      int row = f >> 5, c4 = (f & 31) << 2;
      *(float4*)&Bs[row][c4] = *(const float4*)(W + (size_t)(k0 + row) * N + bn + c4);
    }
    __syncthreads();
#pragma unroll
    for (int kk = 0; kk < 16; ++kk) {
      float a[8], b[8];
      *(float4*)&a[0] = *(float4*)&As[kk][ty * 8];
      *(float4*)&a[4] = *(float4*)&As[kk][ty * 8 + 4];
      *(float4*)&b[0] = *(float4*)&Bs[kk][tx * 8];
      *(float4*)&b[4] = *(float4*)&Bs[kk][tx * 8 + 4];
#pragma unroll
      for (int i = 0; i < 8; ++i)
#pragma unroll
        for (int j = 0; j < 8; ++j) acc[i][j] = fmaf(a[i], b[j], acc[i][j]);
    }
  }
#pragma unroll
  for (int i = 0; i < 8; ++i) {
    int m = bm + ty * 8 + i;
    if (m < M) {
#pragma unroll
      for (int j4 = 0; j4 < 2; ++j4) {
        int n = bn + tx * 8 + j4 * 4;
        float4 bi = *(const float4*)(bias + n);
        float4 o;
        o.x = acc[i][j4 * 4 + 0] + bi.x; o.y = acc[i][j4 * 4 + 1] + bi.y;
        o.z = acc[i][j4 * 4 + 2] + bi.z; o.w = acc[i][j4 * 4 + 3] + bi.w;
        *(float4*)(C + (size_t)m * N + n) = o;
      }
    }
  }
}

// ---------------- LayerNorm over D=512, dual fp32/bf16 out, optional fused SiLU ----------------
__global__ __launch_bounds__(256) void ln_k(
    const float* __restrict__ src, const float* __restrict__ g,
    const float* __restrict__ b, float* __restrict__ out32, u16* __restrict__ out16,
    int rows, int do_silu)
{
  int lane = threadIdx.x & 63, wv = threadIdx.x >> 6;
  int row = (blockIdx.x << 2) + wv;
  if (row >= rows) return;
  const float* p = src + (size_t)row * DD;
  float4 v0 = *(const float4*)(p + lane * 4);
  float4 v1 = *(const float4*)(p + 256 + lane * 4);
  float s = v0.x + v0.y + v0.z + v0.w + v1.x + v1.y + v1.z + v1.w;
  float ss = v0.x*v0.x + v0.y*v0.y + v0.z*v0.z + v0.w*v0.w
           + v1.x*v1.x + v1.y*v1.y + v1.z*v1.z + v1.w*v1.w;
#pragma unroll
  for (int m = 1; m < 64; m <<= 1) { s += __shfl_xor(s, m); ss += __shfl_xor(ss, m); }
  float mean = s * (1.f / 512.f);
  float var = ss * (1.f / 512.f) - mean * mean;
  float rstd = rsqrtf(var + 1e-5f);
  float4 g0 = *(const float4*)(g + lane * 4);
  float4 g1 = *(const float4*)(g + 256 + lane * 4);
  float4 b0 = *(const float4*)(b + lane * 4);
  float4 b1 = *(const float4*)(b + 256 + lane * 4);
  float o[8];
  o[0] = (v0.x - mean) * rstd * g0.x + b0.x;
  o[1] = (v0.y - mean) * rstd * g0.y + b0.y;
  o[2] = (v0.z - mean) * rstd * g0.z + b0.z;
  o[3] = (v0.w - mean) * rstd * g0.w + b0.w;
  o[4] = (v1.x - mean) * rstd * g1.x + b1.x;
  o[5] = (v1.y - mean) * rstd * g1.y + b1.y;
  o[6] = (v1.z - mean) * rstd * g1.z + b1.z;
  o[7] = (v1.w - mean) * rstd * g1.w + b1.w;
  if (do_silu) {
#pragma unroll
    for (int j = 0; j < 8; ++j) o[j] = silu_f(o[j]);
  }
  if (out32) {
    *(float4*)(out32 + (size_t)row * DD + lane * 4) = make_float4(o[0], o[1], o[2], o[3]);
    *(float4*)(out32 + (size_t)row * DD + 256 + lane * 4) = make_float4(o[4], o[5], o[6], o[7]);
  }
  if (out16) {
    u16x4 h0, h1;
#pragma unroll
    for (int j = 0; j < 4; ++j) { h0[j] = f2bf(o[j]); h1[j] = f2bf(o[4 + j]); }
    *(u16x4*)(out16 + (size_t)row * DD + lane * 4) = h0;
    *(u16x4*)(out16 + (size_t)row * DD + 256 + lane * 4) = h1;
  }
}

// ---------------- MFMA flash self-attention ----------------
// q,k: bf16 [B*1024][512] (head slice h*64). vt: bf16 [B*H*64][1024] (pre-transposed V).
// out: bf16 [B*1024][512] = silu(softmax(QK^T/8) V). Scores tiny -> no-max online softmax.
// grid = B*H*8 (q-tiles of 128), block = 256 (4 waves x 32 q-rows).
__global__ __launch_bounds__(256) void attn3_k(
    const u16* __restrict__ q, const u16* __restrict__ k,
    const u16* __restrict__ vt, u16* __restrict__ out)
{
  __shared__ __align__(16) char KVb[2][2][8192];  // [buf][K/V][64x64 bf16, XOR-swizzled]
  __shared__ __align__(16) char QP[16384];        // Q tile [128][64] then per-wave P [32][64]
  __shared__ float Lr[4][32];

  const int t = threadIdx.x, l = t & 63, w = t >> 6;
  const int blk = blockIdx.x;
  const int qt = blk & 7, h = (blk >> 3) & 7, b = blk >> 6;
  const size_t qbase = ((size_t)(b * 1024 + qt * 128)) * 512 + h * 64;
  const size_t kbase = ((size_t)(b * 1024)) * 512 + h * 64;
  const size_t vbase = ((size_t)((b * 8 + h) * 64)) * 1024;

  // ---- stage Q tile [128 rows][64 cols] with pre-swizzled source columns ----
#pragma unroll
  for (int i = 0; i < 4; ++i) {
    int chunk = i * 256 + w * 64 + l;           // lane-varying (l implicit in dest)
    int row = chunk >> 3, c = chunk & 7;
    int cs = c ^ (row & 7);
    gload16(q + qbase + (size_t)row * 512 + cs * 8, QP + (i * 256 + w * 64) * 16);
  }
  // ---- stage K/V tile st into buf ----
  auto stageKV = [&](int st, int buf) {
#pragma unroll
    for (int i = 0; i < 2; ++i) {
      int chunk = i * 256 + w * 64 + l;
      int row = chunk >> 3, c = chunk & 7;
      int cs = c ^ (row & 7);
      gload16(k + kbase + (size_t)(st * 64 + row) * 512 + cs * 8,
              KVb[buf][0] + (i * 256 + w * 64) * 16);
      gload16(vt + vbase + (size_t)row * 1024 + st * 64 + cs * 8,
              KVb[buf][1] + (i * 256 + w * 64) * 16);
    }
  };
  stageKV(0, 0);
  __syncthreads();

  // ---- Q fragments (stay in registers; LDS Q region becomes P after) ----
  s16x8 qf[2][2];
#pragma unroll
  for (int ti = 0; ti < 2; ++ti)
#pragma unroll
    for (int kk = 0; kk < 2; ++kk) {
      int row = w * 32 + ti * 16 + (l & 15);
      int ch = ((l >> 4) + kk * 4) ^ (row & 7);
      qf[ti][kk] = *(const s16x8*)(QP + row * 128 + ch * 16);
    }

  f32x4 oacc[2][4];
#pragma unroll
  for (int qi = 0; qi < 2; ++qi)
#pragma unroll
    for (int dj = 0; dj < 4; ++dj) oacc[qi][dj] = (f32x4){0.f, 0.f, 0.f, 0.f};
  float lsum[2] = {0.f, 0.f};

  int cur = 0;
  for (int st = 0; st < 16; ++st) {
    if (st + 1 < 16) stageKV(st + 1, cur ^ 1);
    // ---- S^T = K @ Q^T : D[s][t], lane holds 4 consecutive s for one t ----
    f32x4 sacc[4][2];
#pragma unroll
    for (int si = 0; si < 4; ++si)
#pragma unroll
      for (int ti = 0; ti < 2; ++ti) sacc[si][ti] = (f32x4){0.f, 0.f, 0.f, 0.f};
#pragma unroll
    for (int si = 0; si < 4; ++si) {
#pragma unroll
      for (int kk = 0; kk < 2; ++kk) {
        int s = si * 16 + (l & 15);
        int ch = ((l >> 4) + kk * 4) ^ (s & 7);
        s16x8 kf = *(const s16x8*)(KVb[cur][0] + s * 128 + ch * 16);
#pragma unroll
        for (int ti = 0; ti < 2; ++ti)
          sacc[si][ti] = __builtin_amdgcn_mfma_f32_16x16x32_bf16(kf, qf[ti][kk], sacc[si][ti], 0, 0, 0);
      }
    }
    // ---- P = exp(S/8), pack to per-wave LDS P[32 t][64 s] (XOR-swizzled), L partials ----
#pragma unroll
    for (int si = 0; si < 4; ++si)
#pragma unroll
      for (int ti = 0; ti < 2; ++ti) {
        float e0 = __expf(sacc[si][ti][0] * 0.125f);
        float e1 = __expf(sacc[si][ti][1] * 0.125f);
        float e2 = __expf(sacc[si][ti][2] * 0.125f);
        float e3 = __expf(sacc[si][ti][3] * 0.125f);
        lsum[ti] += (e0 + e1) + (e2 + e3);
        u16x4 pk; pk[0] = f2bf(e0); pk[1] = f2bf(e1); pk[2] = f2bf(e2); pk[3] = f2bf(e3);
        int tl = ti * 16 + (l & 15);
        int sb = (si * 16 + (l >> 4) * 4) * 2;         // byte offset in row, 8B aligned
        *(u16x4*)(QP + w * 4096 + tl * 128 + (sb ^ ((tl & 7) << 4))) = pk;
      }
    // ---- O += P @ V ----
#pragma unroll
    for (int kk = 0; kk < 2; ++kk) {
      s16x8 pf[2];
#pragma unroll
      for (int qi = 0; qi < 2; ++qi) {
        int tl = qi * 16 + (l & 15);
        int ch = ((l >> 4) + kk * 4) ^ (tl & 7);
        pf[qi] = *(const s16x8*)(QP + w * 4096 + tl * 128 + ch * 16);
      }
#pragma unroll
      for (int dj = 0; dj < 4; ++dj) {
        int d = dj * 16 + (l & 15);
        int ch = ((l >> 4) + kk * 4) ^ (d & 7);
        s16x8 vf = *(const s16x8*)(KVb[cur][1] + d * 128 + ch * 16);
#pragma unroll
        for (int qi = 0; qi < 2; ++qi)
          oacc[qi][dj] = __builtin_amdgcn_mfma_f32_16x16x32_bf16(pf[qi], vf, oacc[qi][dj], 0, 0, 0);
      }
    }
    cur ^= 1;
    __syncthreads();
  }

  // ---- finalize: row sums across lane groups, normalize, silu, write ----
#pragma unroll
  for (int ti = 0; ti < 2; ++ti) {
    lsum[ti] += __shfl_xor(lsum[ti], 16);
    lsum[ti] += __shfl_xor(lsum[ti], 32);
    Lr[w][ti * 16 + (l & 15)] = lsum[ti];
  }
  __syncthreads();
#pragma unroll
  for (int qi = 0; qi < 2; ++qi) {
    float linv[4];
#pragma unroll
    for (int r = 0; r < 4; ++r) linv[r] = 1.f / Lr[w][qi * 16 + (l >> 4) * 4 + r];
#pragma unroll
    for (int dj = 0; dj < 4; ++dj) {
#pragma unroll
      for (int r = 0; r < 4; ++r) {
        int trow = qt * 128 + w * 32 + qi * 16 + (l >> 4) * 4 + r;
        float o = silu_f(oacc[qi][dj][r] * linv[r]);
        out[((size_t)(b * 1024 + trow)) * 512 + h * 64 + dj * 16 + (l & 15)] = f2bf(o);
      }
    }
  }
}

// ---------------- softmax over contiguous rows of 64 (cq), in-place fp32 ----------------
__global__ __launch_bounds__(256) void softmax64_k(float* __restrict__ p, int rows)
{
  int lane = threadIdx.x & 63, wv = threadIdx.x >> 6;
  int row = (blockIdx.x << 2) + wv;
  if (row >= rows) return;
  float x = p[(size_t)row * 64 + lane];
  float m = x;
#pragma unroll
  for (int mk = 1; mk < 64; mk <<= 1) m = fmaxf(m, __shfl_xor(m, mk));
  float e = __expf(x - m);
  float s = e;
#pragma unroll
  for (int mk = 1; mk < 64; mk <<= 1) s += __shfl_xor(s, mk);
  p[(size_t)row * 64 + lane] = e / s;
}

// ---------------- softmax over sequence axis (stride 512), registers + 1R/1W pass ----------------
// grid = B * 32 (16-col groups), block 256 = (16 cols x 16 n-rows). No max (scores bounded).
template<int NL>
__global__ __launch_bounds__(256) void smseq_k(float* __restrict__ p)
{
  __shared__ float red[256];
  int t = threadIdx.x;
  int ci = t & 15, nj = t >> 4;
  int b = blockIdx.x >> 5, cg = blockIdx.x & 31;
  int col = cg * 16 + ci;
  float vals[NL / 16];
  float s = 0.f;
#pragma unroll
  for (int j = 0; j < NL / 16; ++j) {
    float x = __expf(p[((size_t)(b * NL) + nj + j * 16) * 512 + col]);
    vals[j] = x; s += x;
  }
  red[t] = s;
  __syncthreads();
  float tot = 0.f;
#pragma unroll
  for (int j = 0; j < 16; ++j) tot += red[ci + j * 16];
  float inv = 1.f / tot;
#pragma unroll
  for (int j = 0; j < NL / 16; ++j)
    p[((size_t)(b * NL) + nj + j * 16) * 512 + col] = vals[j] * inv;
}

// ---------------- build concat([xw, broadcast(xf_p)]) -> bf16 [B,512,256] ----------------
__global__ __launch_bounds__(256) void build_xc_k(
    const float* __restrict__ xw, const float* __restrict__ xfp, u16* __restrict__ xc)
{
  int idx = blockIdx.x * 256 + threadIdx.x;
  int c = idx & 255, n = (idx >> 8) & 511, b = idx >> 17;
  float val = (n < 256) ? xw[((b << 8) + n) * 256 + c] : xfp[(b << 8) + c];
  xc[idx] = f2bf(val);
}

// ---------------- att[b,h,d,l] = sum_n ck[b,n,h,d]*cv[b,n,h,l] ; grid = B*H ----------------
__global__ __launch_bounds__(256) void attmat_k(
    const float* __restrict__ ckp, const float* __restrict__ cvp,
    float* __restrict__ att, int nlen)
{
  __shared__ float a_s[64][68];
  __shared__ float b_s[64][68];
  int h = blockIdx.x & 7, b = blockIdx.x >> 3;
  int tid = threadIdx.x;
  int d = tid & 63, lg = tid >> 6;
  float acc[16];
#pragma unroll
  for (int j = 0; j < 16; ++j) acc[j] = 0.f;
  for (int n0 = 0; n0 < nlen; n0 += 64) {
    __syncthreads();
#pragma unroll
    for (int i = 0; i < 4; ++i) {
      int f = tid + (i << 8);
      int row = f >> 4, c4 = (f & 15) << 2;
      size_t src = ((size_t)(b * nlen + n0 + row)) * DD + h * 64 + c4;
      *(float4*)&a_s[row][c4] = *(const float4*)(ckp + src);
      *(float4*)&b_s[row][c4] = *(const float4*)(cvp + src);
    }
    __syncthreads();
    for (int nn = 0; nn < 64; ++nn) {
      float av = a_s[nn][d];
#pragma unroll
      for (int j4 = 0; j4 < 4; ++j4) {
        float4 b4 = *(float4*)&b_s[nn][lg * 16 + j4 * 4];
        acc[j4*4+0] = fmaf(av, b4.x, acc[j4*4+0]);
        acc[j4*4+1] = fmaf(av, b4.y, acc[j4*4+1]);
        acc[j4*4+2] = fmaf(av, b4.z, acc[j4*4+2]);
        acc[j4*4+3] = fmaf(av, b4.w, acc[j4*4+3]);
      }
    }
  }
  float* op = att + (size_t)(b * 8 + h) * 4096 + d * 64 + lg * 16;
#pragma unroll
  for (int j4 = 0; j4 < 4; ++j4)
    *(float4*)(op + j4 * 4) = make_float4(acc[j4*4+0], acc[j4*4+1], acc[j4*4+2], acc[j4*4+3]);
}

// ---------------- sy[b,h,l] = sum_s (sum_d sk[b,s,h,d]) * sv[b,s,h,l] ----------------
__global__ __launch_bounds__(64) void sy_k(
    const float* __restrict__ skp, const float* __restrict__ svp, float* __restrict__ sy)
{
  int h = blockIdx.x & 7, b = blockIdx.x >> 3;
  int lane = threadIdx.x;
  float acc = 0.f;
  for (int s = 0; s < 256; ++s) {
    size_t base = ((size_t)(b * 256 + s)) * DD + h * 64 + lane;
    float w = skp[base];
#pragma unroll
    for (int m = 1; m < 64; m <<= 1) w += __shfl_xor(w, m);
    acc = fmaf(w, svp[base], acc);
  }
  sy[(b * 8 + h) * 64 + lane] = acc;
}

// ---------------- out = silu(cq @ att + sy) bf16 ; grid = B*H*16 ----------------
__global__ __launch_bounds__(256) void cy_k(
    const float* __restrict__ cq, const float* __restrict__ att,
    const float* __restrict__ sy, u16* __restrict__ out)
{
  __shared__ float atts[64][68];
  __shared__ float qs[64][68];
  __shared__ float sys[64];
  int blk = blockIdx.x;
  int tt = blk & 15, h = (blk >> 4) & 7, b = blk >> 7;
  int t0 = tt << 6;
  int tid = threadIdx.x;
#pragma unroll
  for (int i = 0; i < 4; ++i) {
    int f = tid + (i << 8);
    int row = f >> 4, c4 = (f & 15) << 2;
    *(float4*)&atts[row][c4] = *(const float4*)(att + (size_t)(b * 8 + h) * 4096 + row * 64 + c4);
    *(float4*)&qs[row][c4] = *(const float4*)(cq + ((size_t)(b * 1024 + t0 + row)) * DD + h * 64 + c4);
  }
  if (tid < 64) sys[tid] = sy[(b * 8 + h) * 64 + tid];
  __syncthreads();
  int r = tid >> 2, lg = tid & 3;
  float acc[16];
#pragma unroll
  for (int j = 0; j < 16; ++j) acc[j] = 0.f;
  for (int d = 0; d < 64; ++d) {
    float qv = qs[r][d];
#pragma unroll
    for (int j4 = 0; j4 < 4; ++j4) {
      float4 a4 = *(float4*)&atts[d][lg * 16 + j4 * 4];
      acc[j4*4+0] = fmaf(qv, a4.x, acc[j4*4+0]);
      acc[j4*4+1] = fmaf(qv, a4.y, acc[j4*4+1]);
      acc[j4*4+2] = fmaf(qv, a4.z, acc[j4*4+2]);
      acc[j4*4+3] = fmaf(qv, a4.w, acc[j4*4+3]);
    }
  }
  u16* op = out + ((size_t)(b * 1024 + t0 + r)) * DD + h * 64 + lg * 16;
#pragma unroll
  for (int j4 = 0; j4 < 4; ++j4) {
    u16x4 o4;
    o4[0] = f2bf(silu_f(acc[j4*4+0] + sys[lg * 16 + j4*4+0]));
    o4[1] = f2bf(silu_f(acc[j4*4+1] + sys[lg * 16 + j4*4+1]));
    o4[2] = f2bf(silu_f(acc[j4*4+2] + sys[lg * 16 + j4*4+2]));
    o4[3] = f2bf(silu_f(acc[j4*4+3] + sys[lg * 16 + j4*4+3]));
    *(u16x4*)(op + j4 * 4) = o4;
  }
}

// ---------------- fp32 -> bf16 elementwise convert ----------------
__global__ __launch_bounds__(256) void cvtf2b_k(const float* __restrict__ in, u16* __restrict__ out, int n)
{
  int i = (blockIdx.x * 256 + threadIdx.x) * 4;
  if (i >= n) return;
  float4 v = *(const float4*)(in + i);
  u16x4 o;
  o[0] = f2bf(v.x); o[1] = f2bf(v.y); o[2] = f2bf(v.z); o[3] = f2bf(v.w);
  *(u16x4*)(out + i) = o;
}

// ---------------- W[K][N] fp32 -> Wt[N][K] bf16 (tiled transpose) ----------------
__global__ __launch_bounds__(256) void wtrans_k(const float* __restrict__ W, u16* __restrict__ Wt, int Kd, int Nd)
{
  __shared__ float tile[32][33];
  int ntn = Nd >> 5;
  int tk = blockIdx.x / ntn, tn = blockIdx.x % ntn;
  int lx = threadIdx.x & 31, ly = threadIdx.x >> 5;
#pragma unroll
  for (int i = 0; i < 4; ++i)
    tile[ly + 8 * i][lx] = W[(size_t)(tk * 32 + ly + 8 * i) * Nd + tn * 32 + lx];
  __syncthreads();
#pragma unroll
  for (int i = 0; i < 4; ++i)
    Wt[(size_t)(tn * 32 + ly + 8 * i) * Kd + tk * 32 + lx] = f2bf(tile[lx][ly + 8 * i]);
}

extern "C" void kernel_launch(void* const* d_in, const int* in_sizes, int n_in,
                              void* d_out, int out_size, void* d_ws, size_t ws_size,
                              hipStream_t stream)
{
  const float* x      = (const float*)d_in[0];
  const float* xf     = (const float*)d_in[1];
  const float* xw     = (const float*)d_in[2];
  const float* xs     = (const float*)d_in[3];
  const float* fp_w   = (const float*)d_in[4];
  const float* fp_b   = (const float*)d_in[5];
  const float* sa_ng  = (const float*)d_in[6];
  const float* sa_nb  = (const float*)d_in[7];
  const float* sa_qw  = (const float*)d_in[8];
  const float* sa_qb  = (const float*)d_in[9];
  const float* sa_kw  = (const float*)d_in[10];
  const float* sa_kb  = (const float*)d_in[11];
  const float* sa_vw  = (const float*)d_in[12];
  const float* sa_vb  = (const float*)d_in[13];
  const float* sa_ow  = (const float*)d_in[14];
  const float* sa_ob  = (const float*)d_in[15];
  const float* ca_ng  = (const float*)d_in[16];
  const float* ca_nb  = (const float*)d_in[17];
  const float* ca_tng = (const float*)d_in[18];
  const float* ca_tnb = (const float*)d_in[19];
  const float* ca_sng = (const float*)d_in[20];
  const float* ca_snb = (const float*)d_in[21];
  const float* ca_qw  = (const float*)d_in[22];
  const float* ca_qb  = (const float*)d_in[23];
  const float* ca_kw  = (const float*)d_in[24];
  const float* ca_kb  = (const float*)d_in[25];
  const float* ca_vw  = (const float*)d_in[26];
  const float* ca_vb  = (const float*)d_in[27];
  const float* ca_apw = (const float*)d_in[28];
  const float* ca_apb = (const float*)d_in[29];
  const float* ca_atw = (const float*)d_in[30];
  const float* ca_atb = (const float*)d_in[31];
  const float* ca_ow  = (const float*)d_in[32];
  const float* ca_ob  = (const float*)d_in[33];
  const float* an_g   = (const float*)d_in[34];
  const float* an_b   = (const float*)d_in[35];
  const float* ffn_w1 = (const float*)d_in[36];
  const float* ffn_b1 = (const float*)d_in[37];
  const float* ffn_w2 = (const float*)d_in[38];
  const float* ffn_b2 = (const float*)d_in[39];
  const float* ffn_ng = (const float*)d_in[40];
  const float* ffn_nb = (const float*)d_in[41];
  const float* ffn_ow = (const float*)d_in[42];
  const float* ffn_ob = (const float*)d_in[43];

  float* ws = (float*)d_ws;
  float* slotZ = ws;                       // z1 -> cq -> z2 -> h2 -> z3   (4M f)
  float* slotP = ws + 4194304;             // xp -> y1 -> y2               (4M f)
  u16* S1 = (u16*)(ws + 8388608);          // xbf -> y1n -> hsb
  u16* S2 = (u16*)(ws + 10485760);         // xn  -> cys
  u16* S3 = (u16*)(ws + 12582912);         // qb  -> y2b
  u16* S4 = (u16*)(ws + 14680064);         // kb
  u16* Vt = (u16*)(ws + 16777216);         // V transposed [B*H*64][1024]
  u16* S6 = (u16*)(ws + 18874368);         // ao
  float* ck  = ws + 20971520;              // 2M f
  float* cv  = ws + 23068672;              // 2M f
  float* sk  = ws + 25165824;              // 1M f
  float* sv  = ws + 26214400;              // 1M f
  float* tnr = ws + 27262976;              // 2M f
  u16* tn = (u16*)(ws + 29360128);         // 2M bf16
  u16* sn = (u16*)(ws + 30408704);         // 1M bf16
  u16* h1 = (u16*)(ws + 20971520);         // 16M bf16, aliases ck..tnr (dead by then)
  u16* xc = (u16*)(ws + 30932992);         // 1M bf16
  float* att = ws + 31457280;              // 256K f
  float* xfp = ws + 31719424;              // 2K f
  float* sy  = ws + 31723520;              // 4K f
  u16* wb = (u16*)(ws + 31727616);         // weights bf16 pool
  u16* fp_wt   = wb;
  u16* sa_qwt  = wb + 262144;
  u16* sa_kwt  = wb + 524288;
  u16* sa_vwt  = wb + 786432;
  u16* sa_owt  = wb + 1048576;
  u16* ca_qwt  = wb + 1310720;
  u16* ca_kwt  = wb + 1572864;
  u16* ca_vwt  = wb + 1835008;
  u16* ca_owt  = wb + 2097152;
  u16* ffn_owt = wb + 2359296;
  u16* ca_atwt = wb + 2621440;             // [512][256]
  u16* ffn_w1t = wb + 2752512;             // [2048][512]
  u16* ffn_w2t = wb + 3801088;             // [512][2048]

  dim3 blk(256);
  auto bgrid = [](int M, int N) { return dim3((unsigned)(N >> 7), (unsigned)(M >> 7)); };

  // ---- conversions ----
  cvtf2b_k<<<dim3(4096), blk, 0, stream>>>(x, S1, 4194304);
  wtrans_k<<<dim3(256), blk, 0, stream>>>(fp_w,   fp_wt,   512, 512);
  wtrans_k<<<dim3(256), blk, 0, stream>>>(sa_qw,  sa_qwt,  512, 512);
  wtrans_k<<<dim3(256), blk, 0, stream>>>(sa_kw,  sa_kwt,  512, 512);
  wtrans_k<<<dim3(256), blk, 0, stream>>>(sa_vw,  sa_vwt,  512, 512);
  wtrans_k<<<dim3(256), blk, 0, stream>>>(sa_ow,  sa_owt,  512, 512);
  wtrans_k<<<dim3(256), blk, 0, stream>>>(ca_qw,  ca_qwt,  512, 512);
  wtrans_k<<<dim3(256), blk, 0, stream>>>(ca_kw,  ca_kwt,  512, 512);
  wtrans_k<<<dim3(256), blk, 0, stream>>>(ca_vw,  ca_vwt,  512, 512);
  wtrans_k<<<dim3(256), blk, 0, stream>>>(ca_ow,  ca_owt,  512, 512);
  wtrans_k<<<dim3(256), blk, 0, stream>>>(ffn_ow, ffn_owt, 512, 512);
  wtrans_k<<<dim3(128), blk, 0, stream>>>(ca_atw, ca_atwt, 256, 512);
  wtrans_k<<<dim3(1024), blk, 0, stream>>>(ffn_w1, ffn_w1t, 512, 2048);
  wtrans_k<<<dim3(1024), blk, 0, stream>>>(ffn_w2, ffn_w2t, 2048, 512);

  // ---- text/audio cross-attn inputs ----
  gemm32_k<<<dim3(2, 1), blk, 0, stream>>>(xf, ca_apw, ca_apb, xfp, 8, 256, 768);
  build_xc_k<<<dim3(4096), blk, 0, stream>>>(xw, xfp, xc);
  gemm_bf<0,0><<<bgrid(4096, 512), blk, 0, stream>>>(xc, ca_atwt, ca_atb, nullptr, 0.f, tnr, nullptr, 4096, 512, 256);
  ln_k<<<dim3(1024), blk, 0, stream>>>(tnr, ca_tng, ca_tnb, nullptr, tn, 4096, 0);
  ln_k<<<dim3(512), blk, 0, stream>>>(xs, ca_sng, ca_snb, nullptr, sn, 2048, 0);

  // ---- feat_proj + self-attention ----
  gemm_bf<0,0><<<bgrid(8192, 512), blk, 0, stream>>>(S1, fp_wt, fp_b, x, 1.f, slotP, nullptr, 8192, 512, 512); // xp
  ln_k<<<dim3(2048), blk, 0, stream>>>(slotP, sa_ng, sa_nb, nullptr, S2, 8192, 0);                             // xn
  gemm_bf<0,1><<<bgrid(8192, 512), blk, 0, stream>>>(S2, sa_qwt, sa_qb, nullptr, 0.f, nullptr, S3, 8192, 512, 512);
  gemm_bf<0,1><<<bgrid(8192, 512), blk, 0, stream>>>(S2, sa_kwt, sa_kb, nullptr, 0.f, nullptr, S4, 8192, 512, 512);
  gemm_bf<0,2><<<bgrid(8192, 512), blk, 0, stream>>>(S2, sa_vwt, sa_vb, nullptr, 0.f, nullptr, Vt, 8192, 512, 512); // V^T
  attn3_k<<<dim3(512), blk, 0, stream>>>(S3, S4, Vt, S6);                                                      // ao=silu(attn)
  gemm_bf<0,0><<<bgrid(8192, 512), blk, 0, stream>>>(S6, sa_owt, sa_ob, slotP, 2.f, slotZ, nullptr, 8192, 512, 512); // z1
  ln_k<<<dim3(2048), blk, 0, stream>>>(slotZ, an_g, an_b, slotP, nullptr, 8192, 0);                            // y1

  // ---- cross-attention ----
  ln_k<<<dim3(2048), blk, 0, stream>>>(slotP, ca_ng, ca_nb, nullptr, S1, 8192, 0);                             // y1n
  gemm_bf<0,0><<<bgrid(8192, 512), blk, 0, stream>>>(S1, ca_qwt, ca_qb, nullptr, 0.f, slotZ, nullptr, 8192, 512, 512); // cq_raw
  softmax64_k<<<dim3(16384), blk, 0, stream>>>(slotZ, 65536);                                                  // cq
  gemm_bf<0,0><<<bgrid(4096, 512), blk, 0, stream>>>(tn, ca_kwt, ca_kb, nullptr, 0.f, ck, nullptr, 4096, 512, 512);
  gemm_bf<0,0><<<bgrid(2048, 512), blk, 0, stream>>>(sn, ca_kwt, ca_kb, nullptr, 0.f, sk, nullptr, 2048, 512, 512);
  gemm_bf<0,0><<<bgrid(4096, 512), blk, 0, stream>>>(tn, ca_vwt, ca_vb, nullptr, 0.f, cv, nullptr, 4096, 512, 512);
  gemm_bf<0,0><<<bgrid(2048, 512), blk, 0, stream>>>(sn, ca_vwt, ca_vb, nullptr, 0.f, sv, nullptr, 2048, 512, 512);
  smseq_k<512><<<dim3(256), blk, 0, stream>>>(ck);
  smseq_k<256><<<dim3(256), blk, 0, stream>>>(sk);
  attmat_k<<<dim3(64), blk, 0, stream>>>(ck, cv, att, 512);
  sy_k<<<dim3(64), dim3(64), 0, stream>>>(sk, sv, sy);
  cy_k<<<dim3(1024), blk, 0, stream>>>(slotZ, att, sy, S2);                                                    // cys=silu(cy+sy)
  gemm_bf<0,0><<<bgrid(8192, 512), blk, 0, stream>>>(S2, ca_owt, ca_ob, slotP, 2.f, slotZ, nullptr, 8192, 512, 512); // z2
  ln_k<<<dim3(2048), blk, 0, stream>>>(slotZ, an_g, an_b, slotP, S3, 8192, 0);                                 // y2 (+bf16)

  // ---- FFN ----
  gemm_bf<1,1><<<bgrid(8192, 2048), blk, 0, stream>>>(S3, ffn_w1t, ffn_b1, nullptr, 0.f, nullptr, h1, 8192, 2048, 512);
  gemm_bf<0,0><<<bgrid(8192, 512), blk, 0, stream>>>(h1, ffn_w2t, ffn_b2, nullptr, 0.f, slotZ, nullptr, 8192, 512, 2048); // h2
  ln_k<<<dim3(2048), blk, 0, stream>>>(slotZ, ffn_ng, ffn_nb, nullptr, S1, 8192, 1);                           // silu(LN(h2))
  gemm_bf<0,0><<<bgrid(8192, 512), blk, 0, stream>>>(S1, ffn_owt, ffn_ob, slotP, 2.f, slotZ, nullptr, 8192, 512, 512); // z3
  ln_k<<<dim3(2048), blk, 0, stream>>>(slotZ, an_g, an_b, (float*)d_out, nullptr, 8192, 0);                    // y3
}

// Round 5
// 481.305 us; speedup vs baseline: 8.4044x; 1.2798x over previous
//
#include <hip/hip_runtime.h>
#include <math.h>

typedef unsigned short u16;
typedef short s16x8 __attribute__((ext_vector_type(8)));
typedef float f32x4 __attribute__((ext_vector_type(4)));
typedef unsigned short u16x8 __attribute__((ext_vector_type(8)));
typedef unsigned short u16x4 __attribute__((ext_vector_type(4)));

#define DD 512

__device__ __forceinline__ float silu_f(float x) { return x / (1.f + __expf(-x)); }
__device__ __forceinline__ float gelu_f(float x) { return 0.5f * x * (1.f + erff(x * 0.7071067811865475f)); }
__device__ __forceinline__ u16 f2bf(float f) {
  unsigned u = __float_as_uint(f);
  return (u16)((u + 0x7fffu + ((u >> 16) & 1u)) >> 16);
}
__device__ __forceinline__ float bf2f(u16 u) { return __uint_as_float(((unsigned)u) << 16); }

__device__ __forceinline__ void gload16(const void* g, void* l) {
  __builtin_amdgcn_global_load_lds(
      (const __attribute__((address_space(1))) void*)(g),
      (__attribute__((address_space(3))) void*)(l), 16, 0, 0);
}

// ---------------- bf16 MFMA GEMM: C[M,N] = act(A[M,K]@W[K,N] + bias) + res_scale*res ----------------
// A: [M,K] bf16 row-major. Bt: [N,K] bf16 row-major. M%128==0, N%128==0, K%32==0.
// ACT: 0 none, 1 exact GELU. OB: 0 fp32 out, 1 bf16 out, 2 bf16 attn-transposed out
// (OB==2: N==512 channels = h*64+d, M = b*1024+t; writes outb as Vt[(b*8+h)*64+d][t], row len 1024)
template<int ACT, int OB>
__global__ __launch_bounds__(256) void gemm_bf(
    const u16* __restrict__ A, const u16* __restrict__ Bt,
    const float* __restrict__ bias, const float* __restrict__ res, float res_scale,
    float* __restrict__ outf, u16* __restrict__ outb, int M, int N, int K)
{
  __shared__ u16 As[128 * 32];
  __shared__ u16 Bs[128 * 32];
  const int t = threadIdx.x, l = t & 63, w = t >> 6;
  const int bm = blockIdx.y << 7, bn = blockIdx.x << 7;
  const int wr = (w >> 1) << 6, wc = (w & 1) << 6;
  f32x4 acc[4][4];
#pragma unroll
  for (int i = 0; i < 4; ++i)
#pragma unroll
    for (int j = 0; j < 4; ++j) acc[i][j] = (f32x4){0.f, 0.f, 0.f, 0.f};

  auto stage = [&](int k0) {
#pragma unroll
    for (int i = 0; i < 2; ++i) {
      int c = t + (i << 8);
      int row = c >> 2, kq = (c & 3) << 3;
      gload16(A + (size_t)(bm + row) * K + k0 + kq, (char*)As + ((w + (i << 2)) << 10));
      gload16(Bt + (size_t)(bn + row) * K + k0 + kq, (char*)Bs + ((w + (i << 2)) << 10));
    }
  };
  stage(0);
  const int fr = l & 15, fk = (l >> 4) << 3;
  for (int k0 = 0;; k0 += 32) {
    __syncthreads();
    s16x8 af[4], bg[4];
#pragma unroll
    for (int i = 0; i < 4; ++i) {
      af[i] = *(const s16x8*)&As[(wr + i * 16 + fr) * 32 + fk];
      bg[i] = *(const s16x8*)&Bs[(wc + i * 16 + fr) * 32 + fk];
    }
    __syncthreads();
    if (k0 + 32 < K) stage(k0 + 32);
#pragma unroll
    for (int mi = 0; mi < 4; ++mi)
#pragma unroll
      for (int ni = 0; ni < 4; ++ni)
        acc[mi][ni] = __builtin_amdgcn_mfma_f32_16x16x32_bf16(af[mi], bg[ni], acc[mi][ni], 0, 0, 0);
    if (k0 + 32 >= K) break;
  }
  const int cr0 = (l >> 4) << 2, cc = l & 15;
#pragma unroll
  for (int ni = 0; ni < 4; ++ni) {
    int n = bn + wc + ni * 16 + cc;
    float bia = bias[n];
    if (OB == 2) {
#pragma unroll
      for (int mi = 0; mi < 4; ++mi) {
        int m0 = bm + wr + mi * 16 + cr0;
        u16x4 pk;
#pragma unroll
        for (int r = 0; r < 4; ++r) pk[r] = f2bf(acc[mi][ni][r] + bia);
        size_t rowp = ((size_t)((m0 >> 10) * 8 + (n >> 6))) * 64 + (n & 63);
        *(u16x4*)(outb + rowp * 1024 + (m0 & 1023)) = pk;
      }
    } else {
#pragma unroll
      for (int mi = 0; mi < 4; ++mi) {
#pragma unroll
        for (int r = 0; r < 4; ++r) {
          int m = bm + wr + mi * 16 + cr0 + r;
          size_t off = (size_t)m * N + n;
          float o = acc[mi][ni][r] + bia;
          if (ACT == 1) o = gelu_f(o);
          if (res) o = fmaf(res_scale, res[off], o);
          if (OB == 1) outb[off] = f2bf(o);
          else outf[off] = o;
        }
      }
    }
  }
}

// ---------------- xf projection: one wave per output element ----------------
// xfp[b*256+n] = dot(xf[b][0:768], apwT[n][0:768]) + bias[n]; grid 512 x 256
__global__ __launch_bounds__(256) void xfp_k(
    const float* __restrict__ xf, const u16* __restrict__ apwT,
    const float* __restrict__ bias, float* __restrict__ xfp)
{
  int wid = blockIdx.x * 4 + (threadIdx.x >> 6);   // 0..2047
  int lane = threadIdx.x & 63;
  int b = wid >> 8, n = wid & 255;
  const u16* wp = apwT + (size_t)n * 768;
  const float* xp = xf + (size_t)b * 768;
  float s = 0.f;
#pragma unroll
  for (int j = 0; j < 12; ++j) s = fmaf(xp[lane + j * 64], bf2f(wp[lane + j * 64]), s);
#pragma unroll
  for (int m = 1; m < 64; m <<= 1) s += __shfl_xor(s, m);
  if (lane == 0) xfp[wid] = s + bias[n];
}

// ---------------- LayerNorm over D=512, dual fp32/bf16 out, optional fused SiLU ----------------
__global__ __launch_bounds__(256) void ln_k(
    const float* __restrict__ src, const float* __restrict__ g,
    const float* __restrict__ b, float* __restrict__ out32, u16* __restrict__ out16,
    int rows, int do_silu)
{
  int lane = threadIdx.x & 63, wv = threadIdx.x >> 6;
  int row = (blockIdx.x << 2) + wv;
  if (row >= rows) return;
  const float* p = src + (size_t)row * DD;
  float4 v0 = *(const float4*)(p + lane * 4);
  float4 v1 = *(const float4*)(p + 256 + lane * 4);
  float s = v0.x + v0.y + v0.z + v0.w + v1.x + v1.y + v1.z + v1.w;
  float ss = v0.x*v0.x + v0.y*v0.y + v0.z*v0.z + v0.w*v0.w
           + v1.x*v1.x + v1.y*v1.y + v1.z*v1.z + v1.w*v1.w;
#pragma unroll
  for (int m = 1; m < 64; m <<= 1) { s += __shfl_xor(s, m); ss += __shfl_xor(ss, m); }
  float mean = s * (1.f / 512.f);
  float var = ss * (1.f / 512.f) - mean * mean;
  float rstd = rsqrtf(var + 1e-5f);
  float4 g0 = *(const float4*)(g + lane * 4);
  float4 g1 = *(const float4*)(g + 256 + lane * 4);
  float4 b0 = *(const float4*)(b + lane * 4);
  float4 b1 = *(const float4*)(b + 256 + lane * 4);
  float o[8];
  o[0] = (v0.x - mean) * rstd * g0.x + b0.x;
  o[1] = (v0.y - mean) * rstd * g0.y + b0.y;
  o[2] = (v0.z - mean) * rstd * g0.z + b0.z;
  o[3] = (v0.w - mean) * rstd * g0.w + b0.w;
  o[4] = (v1.x - mean) * rstd * g1.x + b1.x;
  o[5] = (v1.y - mean) * rstd * g1.y + b1.y;
  o[6] = (v1.z - mean) * rstd * g1.z + b1.z;
  o[7] = (v1.w - mean) * rstd * g1.w + b1.w;
  if (do_silu) {
#pragma unroll
    for (int j = 0; j < 8; ++j) o[j] = silu_f(o[j]);
  }
  if (out32) {
    *(float4*)(out32 + (size_t)row * DD + lane * 4) = make_float4(o[0], o[1], o[2], o[3]);
    *(float4*)(out32 + (size_t)row * DD + 256 + lane * 4) = make_float4(o[4], o[5], o[6], o[7]);
  }
  if (out16) {
    u16x4 h0, h1;
#pragma unroll
    for (int j = 0; j < 4; ++j) { h0[j] = f2bf(o[j]); h1[j] = f2bf(o[4 + j]); }
    *(u16x4*)(out16 + (size_t)row * DD + lane * 4) = h0;
    *(u16x4*)(out16 + (size_t)row * DD + 256 + lane * 4) = h1;
  }
}

// ---------------- MFMA flash self-attention ----------------
// q,k: bf16 [B*1024][512] (head slice h*64). vt: bf16 [B*H*64][1024] (pre-transposed V).
// out: bf16 [B*1024][512] = silu(softmax(QK^T/8) V). Scores tiny -> no-max online softmax.
// grid = B*H*8 (q-tiles of 128), block = 256 (4 waves x 32 q-rows).
__global__ __launch_bounds__(256) void attn3_k(
    const u16* __restrict__ q, const u16* __restrict__ k,
    const u16* __restrict__ vt, u16* __restrict__ out)
{
  __shared__ __align__(16) char KVb[2][2][8192];  // [buf][K/V][64x64 bf16, XOR-swizzled]
  __shared__ __align__(16) char QP[16384];        // Q tile [128][64] then per-wave P [32][64]
  __shared__ float Lr[4][32];

  const int t = threadIdx.x, l = t & 63, w = t >> 6;
  const int blk = blockIdx.x;
  const int qt = blk & 7, h = (blk >> 3) & 7, b = blk >> 6;
  const size_t qbase = ((size_t)(b * 1024 + qt * 128)) * 512 + h * 64;
  const size_t kbase = ((size_t)(b * 1024)) * 512 + h * 64;
  const size_t vbase = ((size_t)((b * 8 + h) * 64)) * 1024;

#pragma unroll
  for (int i = 0; i < 4; ++i) {
    int chunk = i * 256 + w * 64 + l;
    int row = chunk >> 3, c = chunk & 7;
    int cs = c ^ (row & 7);
    gload16(q + qbase + (size_t)row * 512 + cs * 8, QP + (i * 256 + w * 64) * 16);
  }
  auto stageKV = [&](int st, int buf) {
#pragma unroll
    for (int i = 0; i < 2; ++i) {
      int chunk = i * 256 + w * 64 + l;
      int row = chunk >> 3, c = chunk & 7;
      int cs = c ^ (row & 7);
      gload16(k + kbase + (size_t)(st * 64 + row) * 512 + cs * 8,
              KVb[buf][0] + (i * 256 + w * 64) * 16);
      gload16(vt + vbase + (size_t)row * 1024 + st * 64 + cs * 8,
              KVb[buf][1] + (i * 256 + w * 64) * 16);
    }
  };
  stageKV(0, 0);
  __syncthreads();

  s16x8 qf[2][2];
#pragma unroll
  for (int ti = 0; ti < 2; ++ti)
#pragma unroll
    for (int kk = 0; kk < 2; ++kk) {
      int row = w * 32 + ti * 16 + (l & 15);
      int ch = ((l >> 4) + kk * 4) ^ (row & 7);
      qf[ti][kk] = *(const s16x8*)(QP + row * 128 + ch * 16);
    }

  f32x4 oacc[2][4];
#pragma unroll
  for (int qi = 0; qi < 2; ++qi)
#pragma unroll
    for (int dj = 0; dj < 4; ++dj) oacc[qi][dj] = (f32x4){0.f, 0.f, 0.f, 0.f};
  float lsum[2] = {0.f, 0.f};

  int cur = 0;
  for (int st = 0; st < 16; ++st) {
    if (st + 1 < 16) stageKV(st + 1, cur ^ 1);
    f32x4 sacc[4][2];
#pragma unroll
    for (int si = 0; si < 4; ++si)
#pragma unroll
      for (int ti = 0; ti < 2; ++ti) sacc[si][ti] = (f32x4){0.f, 0.f, 0.f, 0.f};
#pragma unroll
    for (int si = 0; si < 4; ++si) {
#pragma unroll
      for (int kk = 0; kk < 2; ++kk) {
        int s = si * 16 + (l & 15);
        int ch = ((l >> 4) + kk * 4) ^ (s & 7);
        s16x8 kf = *(const s16x8*)(KVb[cur][0] + s * 128 + ch * 16);
#pragma unroll
        for (int ti = 0; ti < 2; ++ti)
          sacc[si][ti] = __builtin_amdgcn_mfma_f32_16x16x32_bf16(kf, qf[ti][kk], sacc[si][ti], 0, 0, 0);
      }
    }
#pragma unroll
    for (int si = 0; si < 4; ++si)
#pragma unroll
      for (int ti = 0; ti < 2; ++ti) {
        float e0 = __expf(sacc[si][ti][0] * 0.125f);
        float e1 = __expf(sacc[si][ti][1] * 0.125f);
        float e2 = __expf(sacc[si][ti][2] * 0.125f);
        float e3 = __expf(sacc[si][ti][3] * 0.125f);
        lsum[ti] += (e0 + e1) + (e2 + e3);
        u16x4 pk; pk[0] = f2bf(e0); pk[1] = f2bf(e1); pk[2] = f2bf(e2); pk[3] = f2bf(e3);
        int tl = ti * 16 + (l & 15);
        int sb = (si * 16 + (l >> 4) * 4) * 2;
        *(u16x4*)(QP + w * 4096 + tl * 128 + (sb ^ ((tl & 7) << 4))) = pk;
      }
#pragma unroll
    for (int kk = 0; kk < 2; ++kk) {
      s16x8 pf[2];
#pragma unroll
      for (int qi = 0; qi < 2; ++qi) {
        int tl = qi * 16 + (l & 15);
        int ch = ((l >> 4) + kk * 4) ^ (tl & 7);
        pf[qi] = *(const s16x8*)(QP + w * 4096 + tl * 128 + ch * 16);
      }
#pragma unroll
      for (int dj = 0; dj < 4; ++dj) {
        int d = dj * 16 + (l & 15);
        int ch = ((l >> 4) + kk * 4) ^ (d & 7);
        s16x8 vf = *(const s16x8*)(KVb[cur][1] + d * 128 + ch * 16);
#pragma unroll
        for (int qi = 0; qi < 2; ++qi)
          oacc[qi][dj] = __builtin_amdgcn_mfma_f32_16x16x32_bf16(pf[qi], vf, oacc[qi][dj], 0, 0, 0);
      }
    }
    cur ^= 1;
    __syncthreads();
  }

#pragma unroll
  for (int ti = 0; ti < 2; ++ti) {
    lsum[ti] += __shfl_xor(lsum[ti], 16);
    lsum[ti] += __shfl_xor(lsum[ti], 32);
    Lr[w][ti * 16 + (l & 15)] = lsum[ti];
  }
  __syncthreads();
#pragma unroll
  for (int qi = 0; qi < 2; ++qi) {
    float linv[4];
#pragma unroll
    for (int r = 0; r < 4; ++r) linv[r] = 1.f / Lr[w][qi * 16 + (l >> 4) * 4 + r];
#pragma unroll
    for (int dj = 0; dj < 4; ++dj) {
#pragma unroll
      for (int r = 0; r < 4; ++r) {
        int trow = qt * 128 + w * 32 + qi * 16 + (l >> 4) * 4 + r;
        float o = silu_f(oacc[qi][dj][r] * linv[r]);
        out[((size_t)(b * 1024 + trow)) * 512 + h * 64 + dj * 16 + (l & 15)] = f2bf(o);
      }
    }
  }
}

// ---------------- softmax over contiguous rows of 64 (cq), in-place fp32 ----------------
__global__ __launch_bounds__(256) void softmax64_k(float* __restrict__ p, int rows)
{
  int lane = threadIdx.x & 63, wv = threadIdx.x >> 6;
  int row = (blockIdx.x << 2) + wv;
  if (row >= rows) return;
  float x = p[(size_t)row * 64 + lane];
  float m = x;
#pragma unroll
  for (int mk = 1; mk < 64; mk <<= 1) m = fmaxf(m, __shfl_xor(m, mk));
  float e = __expf(x - m);
  float s = e;
#pragma unroll
  for (int mk = 1; mk < 64; mk <<= 1) s += __shfl_xor(s, mk);
  p[(size_t)row * 64 + lane] = e / s;
}

// ---------------- softmax over sequence axis (stride 512), registers + 1R/1W pass ----------------
template<int NL>
__global__ __launch_bounds__(256) void smseq_k(float* __restrict__ p)
{
  __shared__ float red[256];
  int t = threadIdx.x;
  int ci = t & 15, nj = t >> 4;
  int b = blockIdx.x >> 5, cg = blockIdx.x & 31;
  int col = cg * 16 + ci;
  float vals[NL / 16];
  float s = 0.f;
#pragma unroll
  for (int j = 0; j < NL / 16; ++j) {
    float x = __expf(p[((size_t)(b * NL) + nj + j * 16) * 512 + col]);
    vals[j] = x; s += x;
  }
  red[t] = s;
  __syncthreads();
  float tot = 0.f;
#pragma unroll
  for (int j = 0; j < 16; ++j) tot += red[ci + j * 16];
  float inv = 1.f / tot;
#pragma unroll
  for (int j = 0; j < NL / 16; ++j)
    p[((size_t)(b * NL) + nj + j * 16) * 512 + col] = vals[j] * inv;
}

// ---------------- build concat([xw, broadcast(xf_p)]) -> bf16 [B,512,256] ----------------
__global__ __launch_bounds__(256) void build_xc_k(
    const float* __restrict__ xw, const float* __restrict__ xfp, u16* __restrict__ xc)
{
  int idx = blockIdx.x * 256 + threadIdx.x;
  int c = idx & 255, n = (idx >> 8) & 511, b = idx >> 17;
  float val = (n < 256) ? xw[((b << 8) + n) * 256 + c] : xfp[(b << 8) + c];
  xc[idx] = f2bf(val);
}

// ---------------- att[b,h,d,l] = sum_n ck[b,n,h,d]*cv[b,n,h,l] ; grid = B*H ----------------
__global__ __launch_bounds__(256) void attmat_k(
    const float* __restrict__ ckp, const float* __restrict__ cvp,
    float* __restrict__ att, int nlen)
{
  __shared__ float a_s[64][68];
  __shared__ float b_s[64][68];
  int h = blockIdx.x & 7, b = blockIdx.x >> 3;
  int tid = threadIdx.x;
  int d = tid & 63, lg = tid >> 6;
  float acc[16];
#pragma unroll
  for (int j = 0; j < 16; ++j) acc[j] = 0.f;
  for (int n0 = 0; n0 < nlen; n0 += 64) {
    __syncthreads();
#pragma unroll
    for (int i = 0; i < 4; ++i) {
      int f = tid + (i << 8);
      int row = f >> 4, c4 = (f & 15) << 2;
      size_t src = ((size_t)(b * nlen + n0 + row)) * DD + h * 64 + c4;
      *(float4*)&a_s[row][c4] = *(const float4*)(ckp + src);
      *(float4*)&b_s[row][c4] = *(const float4*)(cvp + src);
    }
    __syncthreads();
    for (int nn = 0; nn < 64; ++nn) {
      float av = a_s[nn][d];
#pragma unroll
      for (int j4 = 0; j4 < 4; ++j4) {
        float4 b4 = *(float4*)&b_s[nn][lg * 16 + j4 * 4];
        acc[j4*4+0] = fmaf(av, b4.x, acc[j4*4+0]);
        acc[j4*4+1] = fmaf(av, b4.y, acc[j4*4+1]);
        acc[j4*4+2] = fmaf(av, b4.z, acc[j4*4+2]);
        acc[j4*4+3] = fmaf(av, b4.w, acc[j4*4+3]);
      }
    }
  }
  float* op = att + (size_t)(b * 8 + h) * 4096 + d * 64 + lg * 16;
#pragma unroll
  for (int j4 = 0; j4 < 4; ++j4)
    *(float4*)(op + j4 * 4) = make_float4(acc[j4*4+0], acc[j4*4+1], acc[j4*4+2], acc[j4*4+3]);
}

// ---------------- sy[b,h,l] = sum_s (sum_d sk[b,s,h,d]) * sv[b,s,h,l] ----------------
__global__ __launch_bounds__(64) void sy_k(
    const float* __restrict__ skp, const float* __restrict__ svp, float* __restrict__ sy)
{
  int h = blockIdx.x & 7, b = blockIdx.x >> 3;
  int lane = threadIdx.x;
  float acc = 0.f;
  for (int s = 0; s < 256; ++s) {
    size_t base = ((size_t)(b * 256 + s)) * DD + h * 64 + lane;
    float w = skp[base];
#pragma unroll
    for (int m = 1; m < 64; m <<= 1) w += __shfl_xor(w, m);
    acc = fmaf(w, svp[base], acc);
  }
  sy[(b * 8 + h) * 64 + lane] = acc;
}

// ---------------- out = silu(cq @ att + sy) bf16 ; grid = B*H*16 ----------------
__global__ __launch_bounds__(256) void cy_k(
    const float* __restrict__ cq, const float* __restrict__ att,
    const float* __restrict__ sy, u16* __restrict__ out)
{
  __shared__ float atts[64][68];
  __shared__ float qs[64][68];
  __shared__ float sys[64];
  int blk = blockIdx.x;
  int tt = blk & 15, h = (blk >> 4) & 7, b = blk >> 7;
  int t0 = tt << 6;
  int tid = threadIdx.x;
#pragma unroll
  for (int i = 0; i < 4; ++i) {
    int f = tid + (i << 8);
    int row = f >> 4, c4 = (f & 15) << 2;
    *(float4*)&atts[row][c4] = *(const float4*)(att + (size_t)(b * 8 + h) * 4096 + row * 64 + c4);
    *(float4*)&qs[row][c4] = *(const float4*)(cq + ((size_t)(b * 1024 + t0 + row)) * DD + h * 64 + c4);
  }
  if (tid < 64) sys[tid] = sy[(b * 8 + h) * 64 + tid];
  __syncthreads();
  int r = tid >> 2, lg = tid & 3;
  float acc[16];
#pragma unroll
  for (int j = 0; j < 16; ++j) acc[j] = 0.f;
  for (int d = 0; d < 64; ++d) {
    float qv = qs[r][d];
#pragma unroll
    for (int j4 = 0; j4 < 4; ++j4) {
      float4 a4 = *(float4*)&atts[d][lg * 16 + j4 * 4];
      acc[j4*4+0] = fmaf(qv, a4.x, acc[j4*4+0]);
      acc[j4*4+1] = fmaf(qv, a4.y, acc[j4*4+1]);
      acc[j4*4+2] = fmaf(qv, a4.z, acc[j4*4+2]);
      acc[j4*4+3] = fmaf(qv, a4.w, acc[j4*4+3]);
    }
  }
  u16* op = out + ((size_t)(b * 1024 + t0 + r)) * DD + h * 64 + lg * 16;
#pragma unroll
  for (int j4 = 0; j4 < 4; ++j4) {
    u16x4 o4;
    o4[0] = f2bf(silu_f(acc[j4*4+0] + sys[lg * 16 + j4*4+0]));
    o4[1] = f2bf(silu_f(acc[j4*4+1] + sys[lg * 16 + j4*4+1]));
    o4[2] = f2bf(silu_f(acc[j4*4+2] + sys[lg * 16 + j4*4+2]));
    o4[3] = f2bf(silu_f(acc[j4*4+3] + sys[lg * 16 + j4*4+3]));
    *(u16x4*)(op + j4 * 4) = o4;
  }
}

// ---------------- fp32 -> bf16 elementwise convert ----------------
__global__ __launch_bounds__(256) void cvtf2b_k(const float* __restrict__ in, u16* __restrict__ out, int n)
{
  int i = (blockIdx.x * 256 + threadIdx.x) * 4;
  if (i >= n) return;
  float4 v = *(const float4*)(in + i);
  u16x4 o;
  o[0] = f2bf(v.x); o[1] = f2bf(v.y); o[2] = f2bf(v.z); o[3] = f2bf(v.w);
  *(u16x4*)(out + i) = o;
}

// ---------------- W[K][N] fp32 -> Wt[N][K] bf16 (tiled transpose), generic ----------------
__global__ __launch_bounds__(256) void wtrans_k(const float* __restrict__ W, u16* __restrict__ Wt, int Kd, int Nd)
{
  __shared__ float tile[32][33];
  int ntn = Nd >> 5;
  int tk = blockIdx.x / ntn, tn = blockIdx.x % ntn;
  int lx = threadIdx.x & 31, ly = threadIdx.x >> 5;
#pragma unroll
  for (int i = 0; i < 4; ++i)
    tile[ly + 8 * i][lx] = W[(size_t)(tk * 32 + ly + 8 * i) * Nd + tn * 32 + lx];
  __syncthreads();
#pragma unroll
  for (int i = 0; i < 4; ++i)
    Wt[(size_t)(tn * 32 + ly + 8 * i) * Kd + tk * 32 + lx] = f2bf(tile[lx][ly + 8 * i]);
}

// ---------------- batched 512x512 transpose of 10 weights in one launch ----------------
struct W10 { const float* w[10]; u16* o[10]; };
__global__ __launch_bounds__(256) void wtrans10_k(W10 p)
{
  __shared__ float tile[32][33];
  int wi = blockIdx.x >> 8;            // 256 tiles per 512x512 weight
  int tb = blockIdx.x & 255;
  int tk = tb >> 4, tn = tb & 15;
  const float* W = p.w[wi];
  u16* Wt = p.o[wi];
  int lx = threadIdx.x & 31, ly = threadIdx.x >> 5;
#pragma unroll
  for (int i = 0; i < 4; ++i)
    tile[ly + 8 * i][lx] = W[(size_t)(tk * 32 + ly + 8 * i) * 512 + tn * 32 + lx];
  __syncthreads();
#pragma unroll
  for (int i = 0; i < 4; ++i)
    Wt[(size_t)(tn * 32 + ly + 8 * i) * 512 + tk * 32 + lx] = f2bf(tile[lx][ly + 8 * i]);
}

extern "C" void kernel_launch(void* const* d_in, const int* in_sizes, int n_in,
                              void* d_out, int out_size, void* d_ws, size_t ws_size,
                              hipStream_t stream)
{
  const float* x      = (const float*)d_in[0];
  const float* xf     = (const float*)d_in[1];
  const float* xw     = (const float*)d_in[2];
  const float* xs     = (const float*)d_in[3];
  const float* fp_w   = (const float*)d_in[4];
  const float* fp_b   = (const float*)d_in[5];
  const float* sa_ng  = (const float*)d_in[6];
  const float* sa_nb  = (const float*)d_in[7];
  const float* sa_qw  = (const float*)d_in[8];
  const float* sa_qb  = (const float*)d_in[9];
  const float* sa_kw  = (const float*)d_in[10];
  const float* sa_kb  = (const float*)d_in[11];
  const float* sa_vw  = (const float*)d_in[12];
  const float* sa_vb  = (const float*)d_in[13];
  const float* sa_ow  = (const float*)d_in[14];
  const float* sa_ob  = (const float*)d_in[15];
  const float* ca_ng  = (const float*)d_in[16];
  const float* ca_nb  = (const float*)d_in[17];
  const float* ca_tng = (const float*)d_in[18];
  const float* ca_tnb = (const float*)d_in[19];
  const float* ca_sng = (const float*)d_in[20];
  const float* ca_snb = (const float*)d_in[21];
  const float* ca_qw  = (const float*)d_in[22];
  const float* ca_qb  = (const float*)d_in[23];
  const float* ca_kw  = (const float*)d_in[24];
  const float* ca_kb  = (const float*)d_in[25];
  const float* ca_vw  = (const float*)d_in[26];
  const float* ca_vb  = (const float*)d_in[27];
  const float* ca_apw = (const float*)d_in[28];
  const float* ca_apb = (const float*)d_in[29];
  const float* ca_atw = (const float*)d_in[30];
  const float* ca_atb = (const float*)d_in[31];
  const float* ca_ow  = (const float*)d_in[32];
  const float* ca_ob  = (const float*)d_in[33];
  const float* an_g   = (const float*)d_in[34];
  const float* an_b   = (const float*)d_in[35];
  const float* ffn_w1 = (const float*)d_in[36];
  const float* ffn_b1 = (const float*)d_in[37];
  const float* ffn_w2 = (const float*)d_in[38];
  const float* ffn_b2 = (const float*)d_in[39];
  const float* ffn_ng = (const float*)d_in[40];
  const float* ffn_nb = (const float*)d_in[41];
  const float* ffn_ow = (const float*)d_in[42];
  const float* ffn_ob = (const float*)d_in[43];

  float* ws = (float*)d_ws;
  float* slotZ = ws;                       // z1 -> cq -> z2 -> h2 -> z3   (4M f)
  float* slotP = ws + 4194304;             // xp -> y1 -> y2               (4M f)
  u16* S1 = (u16*)(ws + 8388608);          // xbf -> y1n -> hsb
  u16* S2 = (u16*)(ws + 10485760);         // xn  -> cys
  u16* S3 = (u16*)(ws + 12582912);         // qb  -> y2b
  u16* S4 = (u16*)(ws + 14680064);         // kb
  u16* Vt = (u16*)(ws + 16777216);         // V transposed [B*H*64][1024]
  u16* S6 = (u16*)(ws + 18874368);         // ao
  // overlay region (fp32): ck|sk contiguous (6144x512), cv|sv contiguous, tnr; h1 aliases later
  float* ck  = ws + 20971520;              // 2M f
  float* sk  = ws + 23068672;              // 1M f
  float* cv  = ws + 24117248;              // 2M f
  float* sv  = ws + 26214400;              // 1M f
  float* tnr = ws + 27262976;              // 2M f
  u16* tn = (u16*)(ws + 29360128);         // 2M bf16 (tn|sn contiguous 6144x512)
  u16* sn = (u16*)(ws + 30408704);         // 1M bf16
  u16* h1 = (u16*)(ws + 20971520);         // 16M bf16, aliases ck..tnr (dead by then)
  u16* xc = (u16*)(ws + 30932992);         // 1M bf16
  float* att = ws + 31457280;              // 256K f
  float* xfp = ws + 31719424;              // 2K f
  float* sy  = ws + 31723520;              // 4K f
  u16* wb = (u16*)(ws + 31727616);         // weights bf16 pool
  u16* fp_wt   = wb;
  u16* sa_qwt  = wb + 262144;
  u16* sa_kwt  = wb + 524288;
  u16* sa_vwt  = wb + 786432;
  u16* sa_owt  = wb + 1048576;
  u16* ca_qwt  = wb + 1310720;
  u16* ca_kwt  = wb + 1572864;
  u16* ca_vwt  = wb + 1835008;
  u16* ca_owt  = wb + 2097152;
  u16* ffn_owt = wb + 2359296;
  u16* ca_atwt = wb + 2621440;             // [512][256]
  u16* ffn_w1t = wb + 2752512;             // [2048][512]
  u16* ffn_w2t = wb + 3801088;             // [512][2048]
  u16* apwT    = wb + 4849664;             // [256][768]

  dim3 blk(256);
  auto bgrid = [](int M, int N) { return dim3((unsigned)(N >> 7), (unsigned)(M >> 7)); };

  // ---- conversions ----
  cvtf2b_k<<<dim3(4096), blk, 0, stream>>>(x, S1, 4194304);
  W10 wp;
  wp.w[0] = fp_w;  wp.o[0] = fp_wt;
  wp.w[1] = sa_qw; wp.o[1] = sa_qwt;
  wp.w[2] = sa_kw; wp.o[2] = sa_kwt;
  wp.w[3] = sa_vw; wp.o[3] = sa_vwt;
  wp.w[4] = sa_ow; wp.o[4] = sa_owt;
  wp.w[5] = ca_qw; wp.o[5] = ca_qwt;
  wp.w[6] = ca_kw; wp.o[6] = ca_kwt;
  wp.w[7] = ca_vw; wp.o[7] = ca_vwt;
  wp.w[8] = ca_ow; wp.o[8] = ca_owt;
  wp.w[9] = ffn_ow; wp.o[9] = ffn_owt;
  wtrans10_k<<<dim3(2560), blk, 0, stream>>>(wp);
  wtrans_k<<<dim3(128), blk, 0, stream>>>(ca_atw, ca_atwt, 256, 512);
  wtrans_k<<<dim3(1024), blk, 0, stream>>>(ffn_w1, ffn_w1t, 512, 2048);
  wtrans_k<<<dim3(1024), blk, 0, stream>>>(ffn_w2, ffn_w2t, 2048, 512);
  wtrans_k<<<dim3(192), blk, 0, stream>>>(ca_apw, apwT, 768, 256);

  // ---- text/audio cross-attn inputs ----
  xfp_k<<<dim3(512), blk, 0, stream>>>(xf, apwT, ca_apb, xfp);
  build_xc_k<<<dim3(4096), blk, 0, stream>>>(xw, xfp, xc);
  gemm_bf<0,0><<<bgrid(4096, 512), blk, 0, stream>>>(xc, ca_atwt, ca_atb, nullptr, 0.f, tnr, nullptr, 4096, 512, 256);
  ln_k<<<dim3(1024), blk, 0, stream>>>(tnr, ca_tng, ca_tnb, nullptr, tn, 4096, 0);
  ln_k<<<dim3(512), blk, 0, stream>>>(xs, ca_sng, ca_snb, nullptr, sn, 2048, 0);

  // ---- feat_proj + self-attention ----
  gemm_bf<0,0><<<bgrid(8192, 512), blk, 0, stream>>>(S1, fp_wt, fp_b, x, 1.f, slotP, nullptr, 8192, 512, 512); // xp
  ln_k<<<dim3(2048), blk, 0, stream>>>(slotP, sa_ng, sa_nb, nullptr, S2, 8192, 0);                             // xn
  gemm_bf<0,1><<<bgrid(8192, 512), blk, 0, stream>>>(S2, sa_qwt, sa_qb, nullptr, 0.f, nullptr, S3, 8192, 512, 512);
  gemm_bf<0,1><<<bgrid(8192, 512), blk, 0, stream>>>(S2, sa_kwt, sa_kb, nullptr, 0.f, nullptr, S4, 8192, 512, 512);
  gemm_bf<0,2><<<bgrid(8192, 512), blk, 0, stream>>>(S2, sa_vwt, sa_vb, nullptr, 0.f, nullptr, Vt, 8192, 512, 512); // V^T
  attn3_k<<<dim3(512), blk, 0, stream>>>(S3, S4, Vt, S6);                                                      // ao=silu(attn)
  gemm_bf<0,0><<<bgrid(8192, 512), blk, 0, stream>>>(S6, sa_owt, sa_ob, slotP, 2.f, slotZ, nullptr, 8192, 512, 512); // z1
  ln_k<<<dim3(2048), blk, 0, stream>>>(slotZ, an_g, an_b, slotP, nullptr, 8192, 0);                            // y1

  // ---- cross-attention ----
  ln_k<<<dim3(2048), blk, 0, stream>>>(slotP, ca_ng, ca_nb, nullptr, S1, 8192, 0);                             // y1n
  gemm_bf<0,0><<<bgrid(8192, 512), blk, 0, stream>>>(S1, ca_qwt, ca_qb, nullptr, 0.f, slotZ, nullptr, 8192, 512, 512); // cq_raw
  softmax64_k<<<dim3(16384), blk, 0, stream>>>(slotZ, 65536);                                                  // cq
  gemm_bf<0,0><<<bgrid(6144, 512), blk, 0, stream>>>(tn, ca_kwt, ca_kb, nullptr, 0.f, ck, nullptr, 6144, 512, 512); // ck|sk
  gemm_bf<0,0><<<bgrid(6144, 512), blk, 0, stream>>>(tn, ca_vwt, ca_vb, nullptr, 0.f, cv, nullptr, 6144, 512, 512); // cv|sv
  smseq_k<512><<<dim3(256), blk, 0, stream>>>(ck);
  smseq_k<256><<<dim3(256), blk, 0, stream>>>(sk);
  attmat_k<<<dim3(64), blk, 0, stream>>>(ck, cv, att, 512);
  sy_k<<<dim3(64), dim3(64), 0, stream>>>(sk, sv, sy);
  cy_k<<<dim3(1024), blk, 0, stream>>>(slotZ, att, sy, S2);                                                    // cys=silu(cy+sy)
  gemm_bf<0,0><<<bgrid(8192, 512), blk, 0, stream>>>(S2, ca_owt, ca_ob, slotP, 2.f, slotZ, nullptr, 8192, 512, 512); // z2
  ln_k<<<dim3(2048), blk, 0, stream>>>(slotZ, an_g, an_b, slotP, S3, 8192, 0);                                 // y2 (+bf16)

  // ---- FFN ----
  gemm_bf<1,1><<<bgrid(8192, 2048), blk, 0, stream>>>(S3, ffn_w1t, ffn_b1, nullptr, 0.f, nullptr, h1, 8192, 2048, 512);
  gemm_bf<0,0><<<bgrid(8192, 512), blk, 0, stream>>>(h1, ffn_w2t, ffn_b2, nullptr, 0.f, slotZ, nullptr, 8192, 512, 2048); // h2
  ln_k<<<dim3(2048), blk, 0, stream>>>(slotZ, ffn_ng, ffn_nb, nullptr, S1, 8192, 1);                           // silu(LN(h2))
  gemm_bf<0,0><<<bgrid(8192, 512), blk, 0, stream>>>(S1, ffn_owt, ffn_ob, slotP, 2.f, slotZ, nullptr, 8192, 512, 512); // z3
  ln_k<<<dim3(2048), blk, 0, stream>>>(slotZ, an_g, an_b, (float*)d_out, nullptr, 8192, 0);                    // y3
}

// Round 6
// 475.144 us; speedup vs baseline: 8.5133x; 1.0130x over previous
//
#include <hip/hip_runtime.h>
#include <math.h>

typedef unsigned short u16;
typedef short s16x8 __attribute__((ext_vector_type(8)));
typedef float f32x4 __attribute__((ext_vector_type(4)));
typedef unsigned short u16x8 __attribute__((ext_vector_type(8)));
typedef unsigned short u16x4 __attribute__((ext_vector_type(4)));

#define DD 512

__device__ __forceinline__ float silu_f(float x) { return x / (1.f + __expf(-x)); }
__device__ __forceinline__ float gelu_f(float x) { return 0.5f * x * (1.f + erff(x * 0.7071067811865475f)); }
__device__ __forceinline__ u16 f2bf(float f) {
  unsigned u = __float_as_uint(f);
  return (u16)((u + 0x7fffu + ((u >> 16) & 1u)) >> 16);
}
__device__ __forceinline__ float bf2f(u16 u) { return __uint_as_float(((unsigned)u) << 16); }

__device__ __forceinline__ void gload16(const void* g, void* l) {
  __builtin_amdgcn_global_load_lds(
      (const __attribute__((address_space(1))) void*)(g),
      (__attribute__((address_space(3))) void*)(l), 16, 0, 0);
}

// ---------------- bf16 MFMA GEMM ----------------
// A: [M,K] bf16 row-major. Bt: [N,K] bf16 row-major. M%128==0, N%128==0, K%32==0.
// ACT: 0 none, 1 exact GELU (fp32/plain-bf16 paths only).
// OB semantics:
//  0: fp32 out -> outf (optional res/res_scale)
//  1: bf16 out -> outb, LDS-coalesced epilogue (ld = N)
//  3: merged QKV (N=1536): n<512 -> outb (plain, ld 512); n<1024 -> outb2 (plain, ld 512);
//     else -> (u16*)outf as Vt[(b*8+h)*64+d][1024] transposed write
//  4: merged fp32 dual (N=1024): n<512 -> outf; else -> outf2 (both ld 512)
template<int ACT, int OB>
__global__ __launch_bounds__(256) void gemm_bf(
    const u16* __restrict__ A, const u16* __restrict__ Bt,
    const float* __restrict__ bias, const float* __restrict__ res, float res_scale,
    float* __restrict__ outf, float* __restrict__ outf2,
    u16* __restrict__ outb, u16* __restrict__ outb2,
    int M, int N, int K)
{
  __shared__ u16 smem[8192];           // As = smem[0..4095], Bs = smem[4096..8191]; reused as epilogue tile
  u16* As = smem;
  u16* Bs = smem + 4096;
  const int t = threadIdx.x, l = t & 63, w = t >> 6;
  const int bm = blockIdx.y << 7, bn = blockIdx.x << 7;
  const int wr = (w >> 1) << 6, wc = (w & 1) << 6;
  f32x4 acc[4][4];
#pragma unroll
  for (int i = 0; i < 4; ++i)
#pragma unroll
    for (int j = 0; j < 4; ++j) acc[i][j] = (f32x4){0.f, 0.f, 0.f, 0.f};

  auto stage = [&](int k0) {
#pragma unroll
    for (int i = 0; i < 2; ++i) {
      int c = t + (i << 8);
      int row = c >> 2, kq = (c & 3) << 3;
      gload16(A + (size_t)(bm + row) * K + k0 + kq, (char*)As + ((w + (i << 2)) << 10));
      gload16(Bt + (size_t)(bn + row) * K + k0 + kq, (char*)Bs + ((w + (i << 2)) << 10));
    }
  };
  stage(0);
  const int fr = l & 15, fk = (l >> 4) << 3;
  for (int k0 = 0;; k0 += 32) {
    __syncthreads();
    s16x8 af[4], bg[4];
#pragma unroll
    for (int i = 0; i < 4; ++i) {
      af[i] = *(const s16x8*)&As[(wr + i * 16 + fr) * 32 + fk];
      bg[i] = *(const s16x8*)&Bs[(wc + i * 16 + fr) * 32 + fk];
    }
    __syncthreads();
    if (k0 + 32 < K) stage(k0 + 32);
#pragma unroll
    for (int mi = 0; mi < 4; ++mi)
#pragma unroll
      for (int ni = 0; ni < 4; ++ni)
        acc[mi][ni] = __builtin_amdgcn_mfma_f32_16x16x32_bf16(af[mi], bg[ni], acc[mi][ni], 0, 0, 0);
    if (k0 + 32 >= K) break;
  }
  const int cr0 = (l >> 4) << 2, cc = l & 15;

  if (OB == 0 || OB == 4) {
    float* fdst = outf;
    int coff = bn, ld = N;
    if (OB == 4) { ld = 512; coff = bn & 511; if (bn >= 512) fdst = outf2; }
#pragma unroll
    for (int ni = 0; ni < 4; ++ni) {
      int n = bn + wc + ni * 16 + cc;
      int col = coff + wc + ni * 16 + cc;
      float bia = bias[n];
#pragma unroll
      for (int mi = 0; mi < 4; ++mi) {
#pragma unroll
        for (int r = 0; r < 4; ++r) {
          int m = bm + wr + mi * 16 + cr0 + r;
          size_t off = (size_t)m * ld + col;
          float o = acc[mi][ni][r] + bia;
          if (ACT == 1) o = gelu_f(o);
          if (res) o = fmaf(res_scale, res[off], o);
          fdst[off] = o;
        }
      }
    }
  } else {
    // bf16 outputs via LDS-coalesced staging
    u16* dst;
    int colbase, ld;
    bool transposed = false;
    if (OB == 1) { dst = outb; colbase = bn; ld = N; }
    else {  // OB == 3
      int seg = bn >> 9;
      colbase = bn & 511; ld = 512;
      if (seg == 0) dst = outb;
      else if (seg == 1) dst = outb2;
      else { dst = (u16*)outf; transposed = true; }
    }
    u16* tile = smem;  // 8192 u16
    if (!transposed) {
#pragma unroll
      for (int mh = 0; mh < 2; ++mh) {
        __syncthreads();
        if ((w >> 1) == mh) {
#pragma unroll
          for (int ni = 0; ni < 4; ++ni) {
            float bia = bias[bn + wc + ni * 16 + cc];
#pragma unroll
            for (int mi = 0; mi < 4; ++mi)
#pragma unroll
              for (int r = 0; r < 4; ++r) {
                float o = acc[mi][ni][r] + bia;
                if (ACT == 1) o = gelu_f(o);
                tile[(mi * 16 + cr0 + r) * 128 + wc + ni * 16 + cc] = f2bf(o);
              }
          }
        }
        __syncthreads();
#pragma unroll
        for (int p = 0; p < 4; ++p) {
          int flat = p * 256 + t;
          int row = flat >> 4, c8 = (flat & 15) << 3;
          *(u16x8*)(dst + (size_t)(bm + mh * 64 + row) * ld + colbase + c8) = *(u16x8*)&tile[row * 128 + c8];
        }
      }
    } else {
      // Vt[(b*8+h)*64+d][1024 t]; tile logical [d-local 64][t-local 128] with XOR swizzle on t index
#pragma unroll
      for (int nh = 0; nh < 2; ++nh) {
        __syncthreads();
        if ((w & 1) == nh) {
#pragma unroll
          for (int ni = 0; ni < 4; ++ni) {
            float bia = bias[bn + wc + ni * 16 + cc];
            int lc = ni * 16 + cc;
#pragma unroll
            for (int mi = 0; mi < 4; ++mi)
#pragma unroll
              for (int r = 0; r < 4; ++r) {
                int lm = wr + mi * 16 + cr0 + r;
                tile[lc * 128 + (lm ^ ((lc & 7) << 4))] = f2bf(acc[mi][ni][r] + bia);
              }
          }
        }
        __syncthreads();
        int h = (colbase + nh * 64) >> 6;
        size_t vrow0 = ((size_t)((bm >> 10) * 8 + h)) * 64;
#pragma unroll
        for (int p = 0; p < 4; ++p) {
          int flat = p * 256 + t;
          int d = flat >> 4, c8 = (flat & 15) << 3;
          *(u16x8*)(dst + (vrow0 + d) * 1024 + (bm & 1023) + c8) =
              *(u16x8*)&tile[d * 128 + (c8 ^ ((d & 7) << 4))];
        }
      }
    }
  }
}

// ---------------- xf projection: one wave per output element ----------------
__global__ __launch_bounds__(256) void xfp_k(
    const float* __restrict__ xf, const u16* __restrict__ apwT,
    const float* __restrict__ bias, float* __restrict__ xfp)
{
  int wid = blockIdx.x * 4 + (threadIdx.x >> 6);
  int lane = threadIdx.x & 63;
  int b = wid >> 8, n = wid & 255;
  const u16* wp = apwT + (size_t)n * 768;
  const float* xp = xf + (size_t)b * 768;
  float s = 0.f;
#pragma unroll
  for (int j = 0; j < 12; ++j) s = fmaf(xp[lane + j * 64], bf2f(wp[lane + j * 64]), s);
#pragma unroll
  for (int m = 1; m < 64; m <<= 1) s += __shfl_xor(s, m);
  if (lane == 0) xfp[wid] = s + bias[n];
}

// ---------------- concat biases: [sa_qb|sa_kb|sa_vb] -> bQKV, [ca_kb|ca_vb] -> bKV ----------------
__global__ __launch_bounds__(256) void biascat_k(
    const float* __restrict__ qb, const float* __restrict__ kb, const float* __restrict__ vb,
    const float* __restrict__ ckb, const float* __restrict__ cvb,
    float* __restrict__ bQKV, float* __restrict__ bKV)
{
  int t = blockIdx.x * 256 + threadIdx.x;
  if (t < 512) bQKV[t] = qb[t];
  else if (t < 1024) bQKV[t] = kb[t - 512];
  else if (t < 1536) bQKV[t] = vb[t - 1024];
  else if (t < 2048) bKV[t - 1536] = ckb[t - 1536];
  else if (t < 2560) bKV[t - 1536] = cvb[t - 2048];
}

// ---------------- LayerNorm over D=512, dual fp32/bf16 out, optional fused SiLU ----------------
__global__ __launch_bounds__(256) void ln_k(
    const float* __restrict__ src, const float* __restrict__ g,
    const float* __restrict__ b, float* __restrict__ out32, u16* __restrict__ out16,
    int rows, int do_silu)
{
  int lane = threadIdx.x & 63, wv = threadIdx.x >> 6;
  int row = (blockIdx.x << 2) + wv;
  if (row >= rows) return;
  const float* p = src + (size_t)row * DD;
  float4 v0 = *(const float4*)(p + lane * 4);
  float4 v1 = *(const float4*)(p + 256 + lane * 4);
  float s = v0.x + v0.y + v0.z + v0.w + v1.x + v1.y + v1.z + v1.w;
  float ss = v0.x*v0.x + v0.y*v0.y + v0.z*v0.z + v0.w*v0.w
           + v1.x*v1.x + v1.y*v1.y + v1.z*v1.z + v1.w*v1.w;
#pragma unroll
  for (int m = 1; m < 64; m <<= 1) { s += __shfl_xor(s, m); ss += __shfl_xor(ss, m); }
  float mean = s * (1.f / 512.f);
  float var = ss * (1.f / 512.f) - mean * mean;
  float rstd = rsqrtf(var + 1e-5f);
  float4 g0 = *(const float4*)(g + lane * 4);
  float4 g1 = *(const float4*)(g + 256 + lane * 4);
  float4 b0 = *(const float4*)(b + lane * 4);
  float4 b1 = *(const float4*)(b + 256 + lane * 4);
  float o[8];
  o[0] = (v0.x - mean) * rstd * g0.x + b0.x;
  o[1] = (v0.y - mean) * rstd * g0.y + b0.y;
  o[2] = (v0.z - mean) * rstd * g0.z + b0.z;
  o[3] = (v0.w - mean) * rstd * g0.w + b0.w;
  o[4] = (v1.x - mean) * rstd * g1.x + b1.x;
  o[5] = (v1.y - mean) * rstd * g1.y + b1.y;
  o[6] = (v1.z - mean) * rstd * g1.z + b1.z;
  o[7] = (v1.w - mean) * rstd * g1.w + b1.w;
  if (do_silu) {
#pragma unroll
    for (int j = 0; j < 8; ++j) o[j] = silu_f(o[j]);
  }
  if (out32) {
    *(float4*)(out32 + (size_t)row * DD + lane * 4) = make_float4(o[0], o[1], o[2], o[3]);
    *(float4*)(out32 + (size_t)row * DD + 256 + lane * 4) = make_float4(o[4], o[5], o[6], o[7]);
  }
  if (out16) {
    u16x4 h0, h1;
#pragma unroll
    for (int j = 0; j < 4; ++j) { h0[j] = f2bf(o[j]); h1[j] = f2bf(o[4 + j]); }
    *(u16x4*)(out16 + (size_t)row * DD + lane * 4) = h0;
    *(u16x4*)(out16 + (size_t)row * DD + 256 + lane * 4) = h1;
  }
}

// ---------------- MFMA flash self-attention ----------------
__global__ __launch_bounds__(256) void attn3_k(
    const u16* __restrict__ q, const u16* __restrict__ k,
    const u16* __restrict__ vt, u16* __restrict__ out)
{
  __shared__ __align__(16) char KVb[2][2][8192];
  __shared__ __align__(16) char QP[16384];
  __shared__ float Lr[4][32];

  const int t = threadIdx.x, l = t & 63, w = t >> 6;
  const int blk = blockIdx.x;
  const int qt = blk & 7, h = (blk >> 3) & 7, b = blk >> 6;
  const size_t qbase = ((size_t)(b * 1024 + qt * 128)) * 512 + h * 64;
  const size_t kbase = ((size_t)(b * 1024)) * 512 + h * 64;
  const size_t vbase = ((size_t)((b * 8 + h) * 64)) * 1024;

#pragma unroll
  for (int i = 0; i < 4; ++i) {
    int chunk = i * 256 + w * 64 + l;
    int row = chunk >> 3, c = chunk & 7;
    int cs = c ^ (row & 7);
    gload16(q + qbase + (size_t)row * 512 + cs * 8, QP + (i * 256 + w * 64) * 16);
  }
  auto stageKV = [&](int st, int buf) {
#pragma unroll
    for (int i = 0; i < 2; ++i) {
      int chunk = i * 256 + w * 64 + l;
      int row = chunk >> 3, c = chunk & 7;
      int cs = c ^ (row & 7);
      gload16(k + kbase + (size_t)(st * 64 + row) * 512 + cs * 8,
              KVb[buf][0] + (i * 256 + w * 64) * 16);
      gload16(vt + vbase + (size_t)row * 1024 + st * 64 + cs * 8,
              KVb[buf][1] + (i * 256 + w * 64) * 16);
    }
  };
  stageKV(0, 0);
  __syncthreads();

  s16x8 qf[2][2];
#pragma unroll
  for (int ti = 0; ti < 2; ++ti)
#pragma unroll
    for (int kk = 0; kk < 2; ++kk) {
      int row = w * 32 + ti * 16 + (l & 15);
      int ch = ((l >> 4) + kk * 4) ^ (row & 7);
      qf[ti][kk] = *(const s16x8*)(QP + row * 128 + ch * 16);
    }

  f32x4 oacc[2][4];
#pragma unroll
  for (int qi = 0; qi < 2; ++qi)
#pragma unroll
    for (int dj = 0; dj < 4; ++dj) oacc[qi][dj] = (f32x4){0.f, 0.f, 0.f, 0.f};
  float lsum[2] = {0.f, 0.f};

  int cur = 0;
  for (int st = 0; st < 16; ++st) {
    if (st + 1 < 16) stageKV(st + 1, cur ^ 1);
    f32x4 sacc[4][2];
#pragma unroll
    for (int si = 0; si < 4; ++si)
#pragma unroll
      for (int ti = 0; ti < 2; ++ti) sacc[si][ti] = (f32x4){0.f, 0.f, 0.f, 0.f};
#pragma unroll
    for (int si = 0; si < 4; ++si) {
#pragma unroll
      for (int kk = 0; kk < 2; ++kk) {
        int s = si * 16 + (l & 15);
        int ch = ((l >> 4) + kk * 4) ^ (s & 7);
        s16x8 kf = *(const s16x8*)(KVb[cur][0] + s * 128 + ch * 16);
#pragma unroll
        for (int ti = 0; ti < 2; ++ti)
          sacc[si][ti] = __builtin_amdgcn_mfma_f32_16x16x32_bf16(kf, qf[ti][kk], sacc[si][ti], 0, 0, 0);
      }
    }
#pragma unroll
    for (int si = 0; si < 4; ++si)
#pragma unroll
      for (int ti = 0; ti < 2; ++ti) {
        float e0 = __expf(sacc[si][ti][0] * 0.125f);
        float e1 = __expf(sacc[si][ti][1] * 0.125f);
        float e2 = __expf(sacc[si][ti][2] * 0.125f);
        float e3 = __expf(sacc[si][ti][3] * 0.125f);
        lsum[ti] += (e0 + e1) + (e2 + e3);
        u16x4 pk; pk[0] = f2bf(e0); pk[1] = f2bf(e1); pk[2] = f2bf(e2); pk[3] = f2bf(e3);
        int tl = ti * 16 + (l & 15);
        int sb = (si * 16 + (l >> 4) * 4) * 2;
        *(u16x4*)(QP + w * 4096 + tl * 128 + (sb ^ ((tl & 7) << 4))) = pk;
      }
#pragma unroll
    for (int kk = 0; kk < 2; ++kk) {
      s16x8 pf[2];
#pragma unroll
      for (int qi = 0; qi < 2; ++qi) {
        int tl = qi * 16 + (l & 15);
        int ch = ((l >> 4) + kk * 4) ^ (tl & 7);
        pf[qi] = *(const s16x8*)(QP + w * 4096 + tl * 128 + ch * 16);
      }
#pragma unroll
      for (int dj = 0; dj < 4; ++dj) {
        int d = dj * 16 + (l & 15);
        int ch = ((l >> 4) + kk * 4) ^ (d & 7);
        s16x8 vf = *(const s16x8*)(KVb[cur][1] + d * 128 + ch * 16);
#pragma unroll
        for (int qi = 0; qi < 2; ++qi)
          oacc[qi][dj] = __builtin_amdgcn_mfma_f32_16x16x32_bf16(pf[qi], vf, oacc[qi][dj], 0, 0, 0);
      }
    }
    cur ^= 1;
    __syncthreads();
  }

#pragma unroll
  for (int ti = 0; ti < 2; ++ti) {
    lsum[ti] += __shfl_xor(lsum[ti], 16);
    lsum[ti] += __shfl_xor(lsum[ti], 32);
    Lr[w][ti * 16 + (l & 15)] = lsum[ti];
  }
  __syncthreads();
  // stage normalized+silu output into QP as u16 [128 t][64 d], then coalesced write
  u16* otile = (u16*)QP;
#pragma unroll
  for (int qi = 0; qi < 2; ++qi) {
    float linv[4];
#pragma unroll
    for (int r = 0; r < 4; ++r) linv[r] = 1.f / Lr[w][qi * 16 + (l >> 4) * 4 + r];
#pragma unroll
    for (int dj = 0; dj < 4; ++dj) {
#pragma unroll
      for (int r = 0; r < 4; ++r) {
        int trl = w * 32 + qi * 16 + (l >> 4) * 4 + r;
        otile[trl * 64 + dj * 16 + (l & 15)] = f2bf(silu_f(oacc[qi][dj][r] * linv[r]));
      }
    }
  }
  __syncthreads();
#pragma unroll
  for (int p = 0; p < 4; ++p) {
    int flat = p * 256 + t;
    int row = flat >> 3, c8 = (flat & 7) << 3;
    *(u16x8*)(out + ((size_t)(b * 1024 + qt * 128 + row)) * 512 + h * 64 + c8) =
        *(u16x8*)&otile[row * 64 + c8];
  }
}

// ---------------- softmax over contiguous rows of 64 (cq), in-place fp32 ----------------
__global__ __launch_bounds__(256) void softmax64_k(float* __restrict__ p, int rows)
{
  int lane = threadIdx.x & 63, wv = threadIdx.x >> 6;
  int row = (blockIdx.x << 2) + wv;
  if (row >= rows) return;
  float x = p[(size_t)row * 64 + lane];
  float m = x;
#pragma unroll
  for (int mk = 1; mk < 64; mk <<= 1) m = fmaxf(m, __shfl_xor(m, mk));
  float e = __expf(x - m);
  float s = e;
#pragma unroll
  for (int mk = 1; mk < 64; mk <<= 1) s += __shfl_xor(s, mk);
  p[(size_t)row * 64 + lane] = e / s;
}

// ---------------- softmax over sequence axis (stride 512), registers + 1R/1W pass ----------------
template<int NL>
__global__ __launch_bounds__(256) void smseq_k(float* __restrict__ p)
{
  __shared__ float red[256];
  int t = threadIdx.x;
  int ci = t & 15, nj = t >> 4;
  int b = blockIdx.x >> 5, cg = blockIdx.x & 31;
  int col = cg * 16 + ci;
  float vals[NL / 16];
  float s = 0.f;
#pragma unroll
  for (int j = 0; j < NL / 16; ++j) {
    float x = __expf(p[((size_t)(b * NL) + nj + j * 16) * 512 + col]);
    vals[j] = x; s += x;
  }
  red[t] = s;
  __syncthreads();
  float tot = 0.f;
#pragma unroll
  for (int j = 0; j < 16; ++j) tot += red[ci + j * 16];
  float inv = 1.f / tot;
#pragma unroll
  for (int j = 0; j < NL / 16; ++j)
    p[((size_t)(b * NL) + nj + j * 16) * 512 + col] = vals[j] * inv;
}

// ---------------- build concat([xw, broadcast(xf_p)]) -> bf16 [B,512,256] ----------------
__global__ __launch_bounds__(256) void build_xc_k(
    const float* __restrict__ xw, const float* __restrict__ xfp, u16* __restrict__ xc)
{
  int idx = blockIdx.x * 256 + threadIdx.x;
  int c = idx & 255, n = (idx >> 8) & 511, b = idx >> 17;
  float val = (n < 256) ? xw[((b << 8) + n) * 256 + c] : xfp[(b << 8) + c];
  xc[idx] = f2bf(val);
}

// ---------------- att[b,h,d,l] = sum_n ck[b,n,h,d]*cv[b,n,h,l] ; grid = B*H ----------------
__global__ __launch_bounds__(256) void attmat_k(
    const float* __restrict__ ckp, const float* __restrict__ cvp,
    float* __restrict__ att, int nlen)
{
  __shared__ float a_s[64][68];
  __shared__ float b_s[64][68];
  int h = blockIdx.x & 7, b = blockIdx.x >> 3;
  int tid = threadIdx.x;
  int d = tid & 63, lg = tid >> 6;
  float acc[16];
#pragma unroll
  for (int j = 0; j < 16; ++j) acc[j] = 0.f;
  for (int n0 = 0; n0 < nlen; n0 += 64) {
    __syncthreads();
#pragma unroll
    for (int i = 0; i < 4; ++i) {
      int f = tid + (i << 8);
      int row = f >> 4, c4 = (f & 15) << 2;
      size_t src = ((size_t)(b * nlen + n0 + row)) * DD + h * 64 + c4;
      *(float4*)&a_s[row][c4] = *(const float4*)(ckp + src);
      *(float4*)&b_s[row][c4] = *(const float4*)(cvp + src);
    }
    __syncthreads();
    for (int nn = 0; nn < 64; ++nn) {
      float av = a_s[nn][d];
#pragma unroll
      for (int j4 = 0; j4 < 4; ++j4) {
        float4 b4 = *(float4*)&b_s[nn][lg * 16 + j4 * 4];
        acc[j4*4+0] = fmaf(av, b4.x, acc[j4*4+0]);
        acc[j4*4+1] = fmaf(av, b4.y, acc[j4*4+1]);
        acc[j4*4+2] = fmaf(av, b4.z, acc[j4*4+2]);
        acc[j4*4+3] = fmaf(av, b4.w, acc[j4*4+3]);
      }
    }
  }
  float* op = att + (size_t)(b * 8 + h) * 4096 + d * 64 + lg * 16;
#pragma unroll
  for (int j4 = 0; j4 < 4; ++j4)
    *(float4*)(op + j4 * 4) = make_float4(acc[j4*4+0], acc[j4*4+1], acc[j4*4+2], acc[j4*4+3]);
}

// ---------------- sy[b,h,l] = sum_s (sum_d sk[b,s,h,d]) * sv[b,s,h,l] ----------------
__global__ __launch_bounds__(64) void sy_k(
    const float* __restrict__ skp, const float* __restrict__ svp, float* __restrict__ sy)
{
  int h = blockIdx.x & 7, b = blockIdx.x >> 3;
  int lane = threadIdx.x;
  float acc = 0.f;
  for (int s = 0; s < 256; ++s) {
    size_t base = ((size_t)(b * 256 + s)) * DD + h * 64 + lane;
    float w = skp[base];
#pragma unroll
    for (int m = 1; m < 64; m <<= 1) w += __shfl_xor(w, m);
    acc = fmaf(w, svp[base], acc);
  }
  sy[(b * 8 + h) * 64 + lane] = acc;
}

// ---------------- out = silu(cq @ att + sy) bf16 ; grid = B*H*16 ----------------
__global__ __launch_bounds__(256) void cy_k(
    const float* __restrict__ cq, const float* __restrict__ att,
    const float* __restrict__ sy, u16* __restrict__ out)
{
  __shared__ float atts[64][68];
  __shared__ float qs[64][68];
  __shared__ float sys[64];
  int blk = blockIdx.x;
  int tt = blk & 15, h = (blk >> 4) & 7, b = blk >> 7;
  int t0 = tt << 6;
  int tid = threadIdx.x;
#pragma unroll
  for (int i = 0; i < 4; ++i) {
    int f = tid + (i << 8);
    int row = f >> 4, c4 = (f & 15) << 2;
    *(float4*)&atts[row][c4] = *(const float4*)(att + (size_t)(b * 8 + h) * 4096 + row * 64 + c4);
    *(float4*)&qs[row][c4] = *(const float4*)(cq + ((size_t)(b * 1024 + t0 + row)) * DD + h * 64 + c4);
  }
  if (tid < 64) sys[tid] = sy[(b * 8 + h) * 64 + tid];
  __syncthreads();
  int r = tid >> 2, lg = tid & 3;
  float acc[16];
#pragma unroll
  for (int j = 0; j < 16; ++j) acc[j] = 0.f;
  for (int d = 0; d < 64; ++d) {
    float qv = qs[r][d];
#pragma unroll
    for (int j4 = 0; j4 < 4; ++j4) {
      float4 a4 = *(float4*)&atts[d][lg * 16 + j4 * 4];
      acc[j4*4+0] = fmaf(qv, a4.x, acc[j4*4+0]);
      acc[j4*4+1] = fmaf(qv, a4.y, acc[j4*4+1]);
      acc[j4*4+2] = fmaf(qv, a4.z, acc[j4*4+2]);
      acc[j4*4+3] = fmaf(qv, a4.w, acc[j4*4+3]);
    }
  }
  u16* op = out + ((size_t)(b * 1024 + t0 + r)) * DD + h * 64 + lg * 16;
#pragma unroll
  for (int j4 = 0; j4 < 4; ++j4) {
    u16x4 o4;
    o4[0] = f2bf(silu_f(acc[j4*4+0] + sys[lg * 16 + j4*4+0]));
    o4[1] = f2bf(silu_f(acc[j4*4+1] + sys[lg * 16 + j4*4+1]));
    o4[2] = f2bf(silu_f(acc[j4*4+2] + sys[lg * 16 + j4*4+2]));
    o4[3] = f2bf(silu_f(acc[j4*4+3] + sys[lg * 16 + j4*4+3]));
    *(u16x4*)(op + j4 * 4) = o4;
  }
}

// ---------------- fp32 -> bf16 elementwise convert ----------------
__global__ __launch_bounds__(256) void cvtf2b_k(const float* __restrict__ in, u16* __restrict__ out, int n)
{
  int i = (blockIdx.x * 256 + threadIdx.x) * 4;
  if (i >= n) return;
  float4 v = *(const float4*)(in + i);
  u16x4 o;
  o[0] = f2bf(v.x); o[1] = f2bf(v.y); o[2] = f2bf(v.z); o[3] = f2bf(v.w);
  *(u16x4*)(out + i) = o;
}

// ---------------- W[K][N] fp32 -> Wt[N][K] bf16 (tiled transpose), generic ----------------
__global__ __launch_bounds__(256) void wtrans_k(const float* __restrict__ W, u16* __restrict__ Wt, int Kd, int Nd)
{
  __shared__ float tile[32][33];
  int ntn = Nd >> 5;
  int tk = blockIdx.x / ntn, tn = blockIdx.x % ntn;
  int lx = threadIdx.x & 31, ly = threadIdx.x >> 5;
#pragma unroll
  for (int i = 0; i < 4; ++i)
    tile[ly + 8 * i][lx] = W[(size_t)(tk * 32 + ly + 8 * i) * Nd + tn * 32 + lx];
  __syncthreads();
#pragma unroll
  for (int i = 0; i < 4; ++i)
    Wt[(size_t)(tn * 32 + ly + 8 * i) * Kd + tk * 32 + lx] = f2bf(tile[lx][ly + 8 * i]);
}

// ---------------- batched 512x512 transpose of 10 weights in one launch ----------------
struct W10 { const float* w[10]; u16* o[10]; };
__global__ __launch_bounds__(256) void wtrans10_k(W10 p)
{
  __shared__ float tile[32][33];
  int wi = blockIdx.x >> 8;
  int tb = blockIdx.x & 255;
  int tk = tb >> 4, tn = tb & 15;
  const float* W = p.w[wi];
  u16* Wt = p.o[wi];
  int lx = threadIdx.x & 31, ly = threadIdx.x >> 5;
#pragma unroll
  for (int i = 0; i < 4; ++i)
    tile[ly + 8 * i][lx] = W[(size_t)(tk * 32 + ly + 8 * i) * 512 + tn * 32 + lx];
  __syncthreads();
#pragma unroll
  for (int i = 0; i < 4; ++i)
    Wt[(size_t)(tn * 32 + ly + 8 * i) * 512 + tk * 32 + lx] = f2bf(tile[lx][ly + 8 * i]);
}

extern "C" void kernel_launch(void* const* d_in, const int* in_sizes, int n_in,
                              void* d_out, int out_size, void* d_ws, size_t ws_size,
                              hipStream_t stream)
{
  const float* x      = (const float*)d_in[0];
  const float* xf     = (const float*)d_in[1];
  const float* xw     = (const float*)d_in[2];
  const float* xs     = (const float*)d_in[3];
  const float* fp_w   = (const float*)d_in[4];
  const float* fp_b   = (const float*)d_in[5];
  const float* sa_ng  = (const float*)d_in[6];
  const float* sa_nb  = (const float*)d_in[7];
  const float* sa_qw  = (const float*)d_in[8];
  const float* sa_qb  = (const float*)d_in[9];
  const float* sa_kw  = (const float*)d_in[10];
  const float* sa_kb  = (const float*)d_in[11];
  const float* sa_vw  = (const float*)d_in[12];
  const float* sa_vb  = (const float*)d_in[13];
  const float* sa_ow  = (const float*)d_in[14];
  const float* sa_ob  = (const float*)d_in[15];
  const float* ca_ng  = (const float*)d_in[16];
  const float* ca_nb  = (const float*)d_in[17];
  const float* ca_tng = (const float*)d_in[18];
  const float* ca_tnb = (const float*)d_in[19];
  const float* ca_sng = (const float*)d_in[20];
  const float* ca_snb = (const float*)d_in[21];
  const float* ca_qw  = (const float*)d_in[22];
  const float* ca_qb  = (const float*)d_in[23];
  const float* ca_kw  = (const float*)d_in[24];
  const float* ca_kb  = (const float*)d_in[25];
  const float* ca_vw  = (const float*)d_in[26];
  const float* ca_vb  = (const float*)d_in[27];
  const float* ca_apw = (const float*)d_in[28];
  const float* ca_apb = (const float*)d_in[29];
  const float* ca_atw = (const float*)d_in[30];
  const float* ca_atb = (const float*)d_in[31];
  const float* ca_ow  = (const float*)d_in[32];
  const float* ca_ob  = (const float*)d_in[33];
  const float* an_g   = (const float*)d_in[34];
  const float* an_b   = (const float*)d_in[35];
  const float* ffn_w1 = (const float*)d_in[36];
  const float* ffn_b1 = (const float*)d_in[37];
  const float* ffn_w2 = (const float*)d_in[38];
  const float* ffn_b2 = (const float*)d_in[39];
  const float* ffn_ng = (const float*)d_in[40];
  const float* ffn_nb = (const float*)d_in[41];
  const float* ffn_ow = (const float*)d_in[42];
  const float* ffn_ob = (const float*)d_in[43];

  float* ws = (float*)d_ws;
  float* slotZ = ws;                       // z1 -> cq -> z2 -> h2 -> z3   (4M f)
  float* slotP = ws + 4194304;             // xp -> y1 -> y2               (4M f)
  u16* S1 = (u16*)(ws + 8388608);          // xbf -> y1n -> hsb
  u16* S2 = (u16*)(ws + 10485760);         // xn  -> cys
  u16* S3 = (u16*)(ws + 12582912);         // qb  -> y2b
  u16* S4 = (u16*)(ws + 14680064);         // kb
  u16* Vt = (u16*)(ws + 16777216);         // V transposed [B*H*64][1024]
  u16* S6 = (u16*)(ws + 18874368);         // ao
  float* ck  = ws + 20971520;              // 2M f (ck|sk contiguous 6144x512)
  float* sk  = ws + 23068672;              // 1M f
  float* cv  = ws + 24117248;              // 2M f (cv|sv contiguous 6144x512)
  float* sv  = ws + 26214400;              // 1M f
  float* tnr = ws + 27262976;              // 2M f
  u16* tn = (u16*)(ws + 29360128);         // 2M bf16 (tn|sn contiguous 6144x512)
  u16* sn = (u16*)(ws + 30408704);         // 1M bf16
  u16* h1 = (u16*)(ws + 20971520);         // 16M bf16, aliases ck..tnr (dead by then)
  u16* xc = (u16*)(ws + 30932992);         // 1M bf16
  float* att = ws + 31457280;              // 256K f
  float* xfp = ws + 31719424;              // 2K f
  float* sy  = ws + 31723520;              // 4K f
  u16* wb = (u16*)(ws + 31727616);         // weights bf16 pool
  u16* fp_wt   = wb;
  u16* sa_qwt  = wb + 262144;              // [sa_qwt|sa_kwt|sa_vwt] contiguous 1536x512
  u16* sa_kwt  = wb + 524288;
  u16* sa_vwt  = wb + 786432;
  u16* sa_owt  = wb + 1048576;
  u16* ca_qwt  = wb + 1310720;
  u16* ca_kwt  = wb + 1572864;             // [ca_kwt|ca_vwt] contiguous 1024x512
  u16* ca_vwt  = wb + 1835008;
  u16* ca_owt  = wb + 2097152;
  u16* ffn_owt = wb + 2359296;
  u16* ca_atwt = wb + 2621440;             // [512][256]
  u16* ffn_w1t = wb + 2752512;             // [2048][512]
  u16* ffn_w2t = wb + 3801088;             // [512][2048]
  u16* apwT    = wb + 4849664;             // [256][768]
  float* bQKV  = (float*)(wb + 5046272);   // 1536 f
  float* bKV   = bQKV + 1536;              // 1024 f

  dim3 blk(256);
  auto bgrid = [](int M, int N) { return dim3((unsigned)(N >> 7), (unsigned)(M >> 7)); };

  // ---- conversions + bias concat ----
  cvtf2b_k<<<dim3(4096), blk, 0, stream>>>(x, S1, 4194304);
  W10 wp;
  wp.w[0] = fp_w;  wp.o[0] = fp_wt;
  wp.w[1] = sa_qw; wp.o[1] = sa_qwt;
  wp.w[2] = sa_kw; wp.o[2] = sa_kwt;
  wp.w[3] = sa_vw; wp.o[3] = sa_vwt;
  wp.w[4] = sa_ow; wp.o[4] = sa_owt;
  wp.w[5] = ca_qw; wp.o[5] = ca_qwt;
  wp.w[6] = ca_kw; wp.o[6] = ca_kwt;
  wp.w[7] = ca_vw; wp.o[7] = ca_vwt;
  wp.w[8] = ca_ow; wp.o[8] = ca_owt;
  wp.w[9] = ffn_ow; wp.o[9] = ffn_owt;
  wtrans10_k<<<dim3(2560), blk, 0, stream>>>(wp);
  wtrans_k<<<dim3(128), blk, 0, stream>>>(ca_atw, ca_atwt, 256, 512);
  wtrans_k<<<dim3(1024), blk, 0, stream>>>(ffn_w1, ffn_w1t, 512, 2048);
  wtrans_k<<<dim3(1024), blk, 0, stream>>>(ffn_w2, ffn_w2t, 2048, 512);
  wtrans_k<<<dim3(192), blk, 0, stream>>>(ca_apw, apwT, 768, 256);
  biascat_k<<<dim3(10), blk, 0, stream>>>(sa_qb, sa_kb, sa_vb, ca_kb, ca_vb, bQKV, bKV);

  // ---- text/audio cross-attn inputs ----
  xfp_k<<<dim3(512), blk, 0, stream>>>(xf, apwT, ca_apb, xfp);
  build_xc_k<<<dim3(4096), blk, 0, stream>>>(xw, xfp, xc);
  gemm_bf<0,0><<<bgrid(4096, 512), blk, 0, stream>>>(xc, ca_atwt, ca_atb, nullptr, 0.f, tnr, nullptr, nullptr, nullptr, 4096, 512, 256);
  ln_k<<<dim3(1024), blk, 0, stream>>>(tnr, ca_tng, ca_tnb, nullptr, tn, 4096, 0);
  ln_k<<<dim3(512), blk, 0, stream>>>(xs, ca_sng, ca_snb, nullptr, sn, 2048, 0);

  // ---- feat_proj + self-attention ----
  gemm_bf<0,0><<<bgrid(8192, 512), blk, 0, stream>>>(S1, fp_wt, fp_b, x, 1.f, slotP, nullptr, nullptr, nullptr, 8192, 512, 512); // xp
  ln_k<<<dim3(2048), blk, 0, stream>>>(slotP, sa_ng, sa_nb, nullptr, S2, 8192, 0);                             // xn
  gemm_bf<0,3><<<bgrid(8192, 1536), blk, 0, stream>>>(S2, sa_qwt, bQKV, nullptr, 0.f, (float*)Vt, nullptr, S3, S4, 8192, 1536, 512); // Q,K,V^T
  attn3_k<<<dim3(512), blk, 0, stream>>>(S3, S4, Vt, S6);                                                      // ao=silu(attn)
  gemm_bf<0,0><<<bgrid(8192, 512), blk, 0, stream>>>(S6, sa_owt, sa_ob, slotP, 2.f, slotZ, nullptr, nullptr, nullptr, 8192, 512, 512); // z1
  ln_k<<<dim3(2048), blk, 0, stream>>>(slotZ, an_g, an_b, slotP, nullptr, 8192, 0);                            // y1

  // ---- cross-attention ----
  ln_k<<<dim3(2048), blk, 0, stream>>>(slotP, ca_ng, ca_nb, nullptr, S1, 8192, 0);                             // y1n
  gemm_bf<0,0><<<bgrid(8192, 512), blk, 0, stream>>>(S1, ca_qwt, ca_qb, nullptr, 0.f, slotZ, nullptr, nullptr, nullptr, 8192, 512, 512); // cq_raw
  softmax64_k<<<dim3(16384), blk, 0, stream>>>(slotZ, 65536);                                                  // cq
  gemm_bf<0,4><<<bgrid(6144, 1024), blk, 0, stream>>>(tn, ca_kwt, bKV, nullptr, 0.f, ck, cv, nullptr, nullptr, 6144, 1024, 512); // ck|sk, cv|sv
  smseq_k<512><<<dim3(256), blk, 0, stream>>>(ck);
  smseq_k<256><<<dim3(256), blk, 0, stream>>>(sk);
  attmat_k<<<dim3(64), blk, 0, stream>>>(ck, cv, att, 512);
  sy_k<<<dim3(64), dim3(64), 0, stream>>>(sk, sv, sy);
  cy_k<<<dim3(1024), blk, 0, stream>>>(slotZ, att, sy, S2);                                                    // cys=silu(cy+sy)
  gemm_bf<0,0><<<bgrid(8192, 512), blk, 0, stream>>>(S2, ca_owt, ca_ob, slotP, 2.f, slotZ, nullptr, nullptr, nullptr, 8192, 512, 512); // z2
  ln_k<<<dim3(2048), blk, 0, stream>>>(slotZ, an_g, an_b, slotP, S3, 8192, 0);                                 // y2 (+bf16)

  // ---- FFN ----
  gemm_bf<1,1><<<bgrid(8192, 2048), blk, 0, stream>>>(S3, ffn_w1t, ffn_b1, nullptr, 0.f, nullptr, nullptr, h1, nullptr, 8192, 2048, 512);
  gemm_bf<0,0><<<bgrid(8192, 512), blk, 0, stream>>>(h1, ffn_w2t, ffn_b2, nullptr, 0.f, slotZ, nullptr, nullptr, nullptr, 8192, 512, 2048); // h2
  ln_k<<<dim3(2048), blk, 0, stream>>>(slotZ, ffn_ng, ffn_nb, nullptr, S1, 8192, 1);                           // silu(LN(h2))
  gemm_bf<0,0><<<bgrid(8192, 512), blk, 0, stream>>>(S1, ffn_owt, ffn_ob, slotP, 2.f, slotZ, nullptr, nullptr, nullptr, 8192, 512, 512); // z3
  ln_k<<<dim3(2048), blk, 0, stream>>>(slotZ, an_g, an_b, (float*)d_out, nullptr, 8192, 0);                    // y3
}